// Round 3
// baseline (773.398 us; speedup 1.0000x reference)
//
#include <hip/hip_runtime.h>
#include <stdint.h>

#define BB 2
#define HH 16
#define LL 2048
#define DD 1024
#define HDD 64
#define NC 512

typedef __bf16 bf16x8 __attribute__((ext_vector_type(8)));
typedef float f32x4 __attribute__((ext_vector_type(4)));
typedef unsigned short u16x8 __attribute__((ext_vector_type(8)));

__device__ __forceinline__ unsigned short f2bf(float f) {
  union { float f; unsigned u; } v; v.f = f;
  unsigned u = v.u;
  u += 0x7fffu + ((u >> 16) & 1u);
  return (unsigned short)(u >> 16);
}
__device__ __forceinline__ float bf2f(unsigned short h) {
  union { unsigned u; float f; } v; v.u = ((unsigned)h) << 16;
  return v.f;
}

// async global->LDS, 16B per lane; lds ptr must be wave-uniform base (HW adds lane*16)
__device__ __forceinline__ void load_lds16(const unsigned short* g, unsigned short* l) {
  __builtin_amdgcn_global_load_lds((const __attribute__((address_space(1))) void*)g,
                                   (__attribute__((address_space(3))) void*)l, 16, 0, 0);
}

// ---------------- cast kernel ----------------
__global__ void cast_all(const float* __restrict__ x, const float* __restrict__ wq,
                         const float* __restrict__ wk, const float* __restrict__ wv,
                         const float* __restrict__ wo, const float* __restrict__ cb,
                         unsigned short* __restrict__ xb, unsigned short* __restrict__ wb,
                         unsigned short* __restrict__ wob, unsigned short* __restrict__ cbb,
                         float* __restrict__ lsum) {
  long i = (long)blockIdx.x * blockDim.x + threadIdx.x;
  if (i == 0) lsum[0] = 0.f;
  const long NX = 4194304, NW = 1048576, NCB = 524288;
  const long TOT = NX + 4 * NW + NCB;
  for (long t = i; t < TOT; t += (long)gridDim.x * blockDim.x) {
    if (t < NX) xb[t] = f2bf(x[t]);
    else if (t < NX + NW) wb[t - NX] = f2bf(wq[t - NX]);
    else if (t < NX + 2 * NW) wb[t - NX] = f2bf(wk[t - NX - NW]);
    else if (t < NX + 3 * NW) wb[t - NX] = f2bf(wv[t - NX - 2 * NW]);
    else if (t < NX + 4 * NW) wob[t - NX - 3 * NW] = f2bf(wo[t - NX - 3 * NW]);
    else cbb[t - NX - 4 * NW] = f2bf(cb[t - NX - 4 * NW]);
  }
}

// ---------------- codebook norms (fp64 accumulate) ----------------
__global__ void c2_kernel(const float* __restrict__ cb, float* __restrict__ c2) {
  int i = blockIdx.x * blockDim.x + threadIdx.x;
  if (i >= HH * NC) return;
  const float* r = cb + (long)i * HDD;
  double s = 0.0;
  for (int j = 0; j < HDD; j++) s += (double)r[j] * (double)r[j];
  c2[i] = (float)s;
}

// ---------------- GEMM1: Q,V = x * W^T (bf16 MFMA), scatter epilogue ----------------
__global__ __launch_bounds__(256) void gemm_qv(
    const unsigned short* __restrict__ xb, const unsigned short* __restrict__ wb,
    unsigned short* __restrict__ qb, unsigned short* __restrict__ vt) {
  __shared__ __align__(16) unsigned short As[128 * 32];
  __shared__ __align__(16) unsigned short Bs[128 * 32];
  int tid = threadIdx.x;
  int wave = tid >> 6, lane = tid & 63;
  int quad = lane >> 4, col = lane & 15;
  int m0 = blockIdx.y * 128;
  // x-blocks 0..7 -> Q columns [0,1024); 8..15 -> V columns [2048,3072)
  int n0 = blockIdx.x * 128 + (blockIdx.x >= 8 ? 1024 : 0);
  f32x4 acc[4][4] = {};
  int row_in = (wave << 4) + (lane >> 2);
  int seg = lane & 3;
  const unsigned short* gA0 = xb + (long)(m0 + row_in) * DD + seg * 8;
  const unsigned short* gA1 = xb + (long)(m0 + 64 + row_in) * DD + seg * 8;
  const unsigned short* gB0 = wb + (long)(n0 + row_in) * DD + seg * 8;
  const unsigned short* gB1 = wb + (long)(n0 + 64 + row_in) * DD + seg * 8;
  unsigned short* lA0 = As + wave * 512;
  unsigned short* lA1 = As + 2048 + wave * 512;
  unsigned short* lB0 = Bs + wave * 512;
  unsigned short* lB1 = Bs + 2048 + wave * 512;
  int wm = wave & 1, wn = wave >> 1;
  const unsigned short* pa = As + (wm * 64 + col) * 32 + quad * 8;
  const unsigned short* pb = Bs + (wn * 64 + col) * 32 + quad * 8;
  for (int kk = 0; kk < DD; kk += 32) {
    __syncthreads();
    load_lds16(gA0 + kk, lA0);
    load_lds16(gA1 + kk, lA1);
    load_lds16(gB0 + kk, lB0);
    load_lds16(gB1 + kk, lB1);
    __syncthreads();
    bf16x8 af[4], bfr[4];
    for (int t = 0; t < 4; t++) af[t]  = *(const bf16x8*)(pa + t * 512);
    for (int t = 0; t < 4; t++) bfr[t] = *(const bf16x8*)(pb + t * 512);
    for (int mt = 0; mt < 4; mt++)
      for (int nt = 0; nt < 4; nt++)
        acc[mt][nt] = __builtin_amdgcn_mfma_f32_16x16x32_bf16(af[mt], bfr[nt], acc[mt][nt], 0, 0, 0);
  }
  for (int mt = 0; mt < 4; mt++)
    for (int nt = 0; nt < 4; nt++) {
      int mbase = m0 + wm * 64 + mt * 16 + quad * 4;
      int n = n0 + wn * 64 + nt * 16 + col;
      int which = n >> 10, e = n & 1023;
      int h = e >> 6, hd = e & 63;
      for (int r = 0; r < 4; r++) {
        int m = mbase + r;
        int b = m >> 11, l = m & 2047;
        unsigned short val = f2bf(acc[mt][nt][r]);
        long bh = (long)(b * HH + h);
        if (which == 0)      qb[(bh * LL + l) * HDD + hd] = val;
        else                 vt[(bh * HDD + hd) * LL + l] = val;
      }
    }
}

// ---------------- fp32 SGEMM: kf[m][e] = sum_d X[m][d] * Wk[e][d] ----------------
// TM=128, TN=64, TK=16; 256 threads, 8x4 register tile per thread.
__global__ __launch_bounds__(256) void kgemm_f32(
    const float* __restrict__ X, const float* __restrict__ W,
    float* __restrict__ kf) {
  __shared__ float As[16][128];
  __shared__ float Bs[16][64];
  int tid = threadIdx.x;
  int n0 = blockIdx.x * 64;
  int m0 = blockIdx.y * 128;
  int am = tid >> 2;             // 0..63 (two halves)
  int ak4 = (tid & 3) * 4;
  int tn = tid & 15, tm = tid >> 4;
  float acc[8][4] = {};
  const float* pA0 = X + (long)(m0 + am) * DD + ak4;
  const float* pA1 = X + (long)(m0 + 64 + am) * DD + ak4;
  const float* pB  = W + (long)(n0 + am) * DD + ak4;
  float4 xa0 = *(const float4*)(pA0);
  float4 xa1 = *(const float4*)(pA1);
  float4 wb0 = *(const float4*)(pB);
  for (int k0 = 0; k0 < DD; k0 += 16) {
    __syncthreads();
#pragma unroll
    for (int j = 0; j < 4; j++) {
      As[ak4 + j][am]      = ((const float*)&xa0)[j];
      As[ak4 + j][64 + am] = ((const float*)&xa1)[j];
      Bs[ak4 + j][am]      = ((const float*)&wb0)[j];
    }
    __syncthreads();
    if (k0 + 16 < DD) {
      xa0 = *(const float4*)(pA0 + k0 + 16);
      xa1 = *(const float4*)(pA1 + k0 + 16);
      wb0 = *(const float4*)(pB + k0 + 16);
    }
#pragma unroll
    for (int k = 0; k < 16; k++) {
      float4 a0 = *(const float4*)&As[k][tm * 8];
      float4 a1 = *(const float4*)&As[k][tm * 8 + 4];
      float4 bv = *(const float4*)&Bs[k][tn * 4];
#pragma unroll
      for (int i = 0; i < 4; i++)
#pragma unroll
        for (int j = 0; j < 4; j++) {
          acc[i][j]     = fmaf(((const float*)&a0)[i], ((const float*)&bv)[j], acc[i][j]);
          acc[4 + i][j] = fmaf(((const float*)&a1)[i], ((const float*)&bv)[j], acc[4 + i][j]);
        }
    }
  }
  int h = n0 >> 6;
#pragma unroll
  for (int i = 0; i < 8; i++) {
    int m = m0 + tm * 8 + i;
    int b = m >> 11, l = m & 2047;
    float4 o;
    ((float*)&o)[0] = acc[i][0]; ((float*)&o)[1] = acc[i][1];
    ((float*)&o)[2] = acc[i][2]; ((float*)&o)[3] = acc[i][3];
    *(float4*)(kf + (((long)(b * HH + h) * LL + l) * HDD) + tn * 4) = o;
  }
}

// ---------------- fp32 VQ: one thread per k-row; codes split across 4 waves ----------------
__global__ __launch_bounds__(256) void vq_f32(
    const float* __restrict__ kf, const float* __restrict__ cb,
    const float* __restrict__ c2, const unsigned short* __restrict__ cbb,
    unsigned short* __restrict__ khat, float* __restrict__ scodes,
    float* __restrict__ lsum) {
  __shared__ float bvals[4][64];
  __shared__ int bidxs[4][64];
  int tid = threadIdx.x, lane = tid & 63;
  int w = tid >> 6;
  int blk = blockIdx.x;
  int bh = blk >> 5, rb = blk & 31;
  int h = bh & 15;
  int row = rb * 64 + lane;
  const float* krow = kf + ((long)bh * LL + row) * HDD;
  float kr[64];
#pragma unroll
  for (int j = 0; j < 16; j++) {
    float4 t = *(const float4*)(krow + j * 4);
    kr[j * 4] = t.x; kr[j * 4 + 1] = t.y; kr[j * 4 + 2] = t.z; kr[j * 4 + 3] = t.w;
  }
  const float* cbh = cb + (long)h * NC * HDD;
  const float* c2h = c2 + h * NC;
  float best = 1e38f; int bidx = 0;
  for (int i = 0; i < 128; i++) {
    int c = w * 128 + i;
    const float* cp = cbh + c * 64;
    float d0 = 0.f, d1 = 0.f, d2a = 0.f, d3 = 0.f;
#pragma unroll
    for (int j = 0; j < 16; j++) {
      float4 cv = *(const float4*)(cp + j * 4);
      d0  = fmaf(kr[4 * j],     cv.x, d0);
      d1  = fmaf(kr[4 * j + 1], cv.y, d1);
      d2a = fmaf(kr[4 * j + 2], cv.z, d2a);
      d3  = fmaf(kr[4 * j + 3], cv.w, d3);
    }
    float dot = (d0 + d1) + (d2a + d3);
    float val = c2h[c] - 2.0f * dot;
    if (val < best) { best = val; bidx = c; }
  }
  bvals[w][lane] = best; bidxs[w][lane] = bidx;
  __syncthreads();
  if (tid < 64) {
    best = bvals[0][lane]; bidx = bidxs[0][lane];
#pragma unroll
    for (int ww = 1; ww < 4; ww++) {
      float v = bvals[ww][lane]; int ii = bidxs[ww][lane];
      if (v < best) { best = v; bidx = ii; }   // strict < keeps lowest code range on ties
    }
    float k2 = 0.f;
#pragma unroll
    for (int j = 0; j < 64; j++) k2 = fmaf(kr[j], kr[j], k2);
    float d2v = k2 + best;
    float part = d2v;
    part += __shfl_xor(part, 1);  part += __shfl_xor(part, 2);
    part += __shfl_xor(part, 4);  part += __shfl_xor(part, 8);
    part += __shfl_xor(part, 16); part += __shfl_xor(part, 32);
    if (lane == 0) atomicAdd(lsum, part);
    scodes[(long)bh * LL + row] = (float)bidx;
    const unsigned short* crow = cbb + ((long)h * NC + bidx) * HDD;
    unsigned short* orow = khat + ((long)bh * LL + row) * HDD;
#pragma unroll
    for (int j = 0; j < 8; j++)
      *(u16x8*)(orow + j * 8) = *(const u16x8*)(crow + j * 8);
  }
}

// ---------------- flash attention ----------------
__global__ __launch_bounds__(256) void attn_kernel(
    const unsigned short* __restrict__ qb, const unsigned short* __restrict__ khat,
    const unsigned short* __restrict__ vt, unsigned short* __restrict__ attnb) {
  __shared__ __align__(16) unsigned short Pbuf[4][16 * 72];
  int tid = threadIdx.x, wave = tid >> 6, lane = tid & 63;
  int quad = lane >> 4, col = lane & 15;
  int qt = blockIdx.x;
  int bh = blockIdx.y;
  int b = bh >> 4, h = bh & 15;
  int qbase = qt * 64 + wave * 16;
  const unsigned short* qrow = qb + ((long)bh * LL + qbase + col) * HDD;
  bf16x8 aq0 = *(const bf16x8*)(qrow + quad * 8);
  bf16x8 aq1 = *(const bf16x8*)(qrow + 32 + quad * 8);
  float mrow[4] = {-1e30f, -1e30f, -1e30f, -1e30f};
  float lrow[4] = {0.f, 0.f, 0.f, 0.f};
  f32x4 oacc[4] = {};
  unsigned short* P = Pbuf[wave];
  const unsigned short* kh = khat + (long)bh * LL * HDD;
  const unsigned short* vh = vt + (long)bh * HDD * LL;
  for (int kt = 0; kt <= qt; kt++) {
    int kbase = kt * 64;
    float sc[4][4];
    for (int nt = 0; nt < 4; nt++) {
      const unsigned short* krow = kh + (long)(kbase + nt * 16 + col) * HDD;
      bf16x8 b0 = *(const bf16x8*)(krow + quad * 8);
      bf16x8 b1 = *(const bf16x8*)(krow + 32 + quad * 8);
      f32x4 z = {};
      z = __builtin_amdgcn_mfma_f32_16x16x32_bf16(aq0, b0, z, 0, 0, 0);
      z = __builtin_amdgcn_mfma_f32_16x16x32_bf16(aq1, b1, z, 0, 0, 0);
      for (int r = 0; r < 4; r++) sc[nt][r] = z[r] * 0.125f;
    }
    if (kt == qt) {
      for (int nt = 0; nt < 4; nt++) {
        int key = kbase + nt * 16 + col;
        for (int r = 0; r < 4; r++) {
          int qr = qbase + quad * 4 + r;
          if (key > qr) sc[nt][r] = -1e30f;
        }
      }
    }
    float alpha[4];
    for (int r = 0; r < 4; r++) {
      float mx = fmaxf(fmaxf(sc[0][r], sc[1][r]), fmaxf(sc[2][r], sc[3][r]));
      mx = fmaxf(mx, __shfl_xor(mx, 1));
      mx = fmaxf(mx, __shfl_xor(mx, 2));
      mx = fmaxf(mx, __shfl_xor(mx, 4));
      mx = fmaxf(mx, __shfl_xor(mx, 8));
      float mnew = fmaxf(mrow[r], mx);
      alpha[r] = __expf(mrow[r] - mnew);
      mrow[r] = mnew;
    }
    float ts[4] = {0.f, 0.f, 0.f, 0.f};
    for (int nt = 0; nt < 4; nt++)
      for (int r = 0; r < 4; r++) {
        float p = __expf(sc[nt][r] - mrow[r]);
        ts[r] += p;
        P[(quad * 4 + r) * 72 + nt * 16 + col] = f2bf(p);
      }
    for (int r = 0; r < 4; r++) {
      float t = ts[r];
      t += __shfl_xor(t, 1); t += __shfl_xor(t, 2);
      t += __shfl_xor(t, 4); t += __shfl_xor(t, 8);
      lrow[r] = lrow[r] * alpha[r] + t;
    }
    for (int nt = 0; nt < 4; nt++)
      for (int r = 0; r < 4; r++) oacc[nt][r] *= alpha[r];
    bf16x8 ap0 = *(const bf16x8*)(P + col * 72 + quad * 8);
    bf16x8 ap1 = *(const bf16x8*)(P + col * 72 + 32 + quad * 8);
    for (int nt = 0; nt < 4; nt++) {
      const unsigned short* vrow = vh + (long)(nt * 16 + col) * LL + kbase;
      bf16x8 v0 = *(const bf16x8*)(vrow + quad * 8);
      bf16x8 v1 = *(const bf16x8*)(vrow + 32 + quad * 8);
      oacc[nt] = __builtin_amdgcn_mfma_f32_16x16x32_bf16(ap0, v0, oacc[nt], 0, 0, 0);
      oacc[nt] = __builtin_amdgcn_mfma_f32_16x16x32_bf16(ap1, v1, oacc[nt], 0, 0, 0);
    }
  }
  for (int r = 0; r < 4; r++) {
    int row = qbase + quad * 4 + r;
    float inv = 1.0f / lrow[r];
    for (int nt = 0; nt < 4; nt++) {
      int hd = nt * 16 + col;
      attnb[((long)b * LL + row) * DD + h * HDD + hd] = f2bf(oacc[nt][r] * inv);
    }
  }
}

// ---------------- GEMM2: out = attn * Wo^T (fp32 store) ----------------
__global__ __launch_bounds__(256) void gemm_out(
    const unsigned short* __restrict__ attnb, const unsigned short* __restrict__ wob,
    float* __restrict__ out) {
  __shared__ __align__(16) unsigned short As[128 * 32];
  __shared__ __align__(16) unsigned short Bs[128 * 32];
  int tid = threadIdx.x;
  int wave = tid >> 6, lane = tid & 63;
  int quad = lane >> 4, col = lane & 15;
  int m0 = blockIdx.y * 128;
  int n0 = blockIdx.x * 128;
  f32x4 acc[4][4] = {};
  int row_in = (wave << 4) + (lane >> 2);
  int seg = lane & 3;
  const unsigned short* gA0 = attnb + (long)(m0 + row_in) * DD + seg * 8;
  const unsigned short* gA1 = attnb + (long)(m0 + 64 + row_in) * DD + seg * 8;
  const unsigned short* gB0 = wob + (long)(n0 + row_in) * DD + seg * 8;
  const unsigned short* gB1 = wob + (long)(n0 + 64 + row_in) * DD + seg * 8;
  unsigned short* lA0 = As + wave * 512;
  unsigned short* lA1 = As + 2048 + wave * 512;
  unsigned short* lB0 = Bs + wave * 512;
  unsigned short* lB1 = Bs + 2048 + wave * 512;
  int wm = wave & 1, wn = wave >> 1;
  const unsigned short* pa = As + (wm * 64 + col) * 32 + quad * 8;
  const unsigned short* pb = Bs + (wn * 64 + col) * 32 + quad * 8;
  for (int kk = 0; kk < DD; kk += 32) {
    __syncthreads();
    load_lds16(gA0 + kk, lA0);
    load_lds16(gA1 + kk, lA1);
    load_lds16(gB0 + kk, lB0);
    load_lds16(gB1 + kk, lB1);
    __syncthreads();
    bf16x8 af[4], bfr[4];
    for (int t = 0; t < 4; t++) af[t]  = *(const bf16x8*)(pa + t * 512);
    for (int t = 0; t < 4; t++) bfr[t] = *(const bf16x8*)(pb + t * 512);
    for (int mt = 0; mt < 4; mt++)
      for (int nt = 0; nt < 4; nt++)
        acc[mt][nt] = __builtin_amdgcn_mfma_f32_16x16x32_bf16(af[mt], bfr[nt], acc[mt][nt], 0, 0, 0);
  }
  for (int mt = 0; mt < 4; mt++)
    for (int nt = 0; nt < 4; nt++) {
      int mbase = m0 + wm * 64 + mt * 16 + quad * 4;
      int n = n0 + wn * 64 + nt * 16 + col;
      for (int r = 0; r < 4; r++)
        out[(long)(mbase + r) * DD + n] = acc[mt][nt][r];
    }
}

// ---------------- finalize scalars ----------------
__global__ void finalize(const float* __restrict__ lsum, float* __restrict__ out) {
  if (threadIdx.x == 0) {
    float v = lsum[0] / (float)(BB * HH * LL);
    out[4194304] = v;
    out[4194305] = v;
  }
}

extern "C" void kernel_launch(void* const* d_in, const int* in_sizes, int n_in,
                              void* d_out, int out_size, void* d_ws, size_t ws_size,
                              hipStream_t stream) {
  const float* x  = (const float*)d_in[0];
  const float* wq = (const float*)d_in[1];
  const float* wk = (const float*)d_in[2];
  const float* wv = (const float*)d_in[3];
  const float* wo = (const float*)d_in[4];
  const float* cb = (const float*)d_in[5];
  float* out = (float*)d_out;

  char* ws = (char*)d_ws;
  size_t off = 0;
  auto alloc = [&](size_t bytes) {
    void* p = ws + off;
    off = (off + bytes + 255) & ~(size_t)255;
    return p;
  };
  unsigned short* xb    = (unsigned short*)alloc(4194304 * 2);
  unsigned short* wb    = (unsigned short*)alloc(3145728 * 2);
  unsigned short* wob   = (unsigned short*)alloc(1048576 * 2);
  unsigned short* cbb   = (unsigned short*)alloc(524288 * 2);
  unsigned short* qb    = (unsigned short*)alloc(4194304 * 2);
  unsigned short* vt    = (unsigned short*)alloc(4194304 * 2);
  unsigned short* khat  = (unsigned short*)alloc(4194304 * 2);
  unsigned short* attnb = (unsigned short*)alloc(4194304 * 2);
  float* kf   = (float*)alloc(4194304 * 4);
  float* c2   = (float*)alloc(8192 * 4);
  float* lsum = (float*)alloc(256);

  cast_all<<<dim3(4096), dim3(256), 0, stream>>>(x, wq, wk, wv, wo, cb, xb, wb, wob, cbb, lsum);
  c2_kernel<<<dim3(32), dim3(256), 0, stream>>>(cb, c2);
  gemm_qv<<<dim3(16, 32), dim3(256), 0, stream>>>(xb, wb, qb, vt);
  kgemm_f32<<<dim3(16, 32), dim3(256), 0, stream>>>(x, wk, kf);
  vq_f32<<<dim3(1024), dim3(256), 0, stream>>>(kf, cb, c2, cbb, khat, out + 4194306, lsum);
  attn_kernel<<<dim3(32, 32), dim3(256), 0, stream>>>(qb, khat, vt, attnb);
  gemm_out<<<dim3(8, 32), dim3(256), 0, stream>>>(attnb, wob, out);
  finalize<<<dim3(1), dim3(64), 0, stream>>>(lsum, out);
}

// Round 4
// 574.659 us; speedup vs baseline: 1.3458x; 1.3458x over previous
//
#include <hip/hip_runtime.h>
#include <stdint.h>

#define BB 2
#define HH 16
#define LL 2048
#define DD 1024
#define HDD 64
#define NC 512

typedef __bf16 bf16x8 __attribute__((ext_vector_type(8)));
typedef float f32x4 __attribute__((ext_vector_type(4)));
typedef unsigned short u16x8 __attribute__((ext_vector_type(8)));

__device__ __forceinline__ unsigned short f2bf(float f) {
  union { float f; unsigned u; } v; v.f = f;
  unsigned u = v.u;
  u += 0x7fffu + ((u >> 16) & 1u);
  return (unsigned short)(u >> 16);
}
__device__ __forceinline__ float bf2f(unsigned short h) {
  union { unsigned u; float f; } v; v.u = ((unsigned)h) << 16;
  return v.f;
}

// async global->LDS, 16B per lane; lds ptr must be wave-uniform base (HW adds lane*16)
__device__ __forceinline__ void load_lds16(const unsigned short* g, unsigned short* l) {
  __builtin_amdgcn_global_load_lds((const __attribute__((address_space(1))) void*)g,
                                   (__attribute__((address_space(3))) void*)l, 16, 0, 0);
}

// ---------------- cast kernel ----------------
__global__ void cast_all(const float* __restrict__ x, const float* __restrict__ wq,
                         const float* __restrict__ wk, const float* __restrict__ wv,
                         const float* __restrict__ wo, const float* __restrict__ cb,
                         unsigned short* __restrict__ xb, unsigned short* __restrict__ wb,
                         unsigned short* __restrict__ wob, unsigned short* __restrict__ cbb,
                         float* __restrict__ lsum) {
  long i = (long)blockIdx.x * blockDim.x + threadIdx.x;
  if (i == 0) lsum[0] = 0.f;
  const long NX = 4194304, NW = 1048576, NCB = 524288;
  const long TOT = NX + 4 * NW + NCB;
  for (long t = i; t < TOT; t += (long)gridDim.x * blockDim.x) {
    if (t < NX) xb[t] = f2bf(x[t]);
    else if (t < NX + NW) wb[t - NX] = f2bf(wq[t - NX]);
    else if (t < NX + 2 * NW) wb[t - NX] = f2bf(wk[t - NX - NW]);
    else if (t < NX + 3 * NW) wb[t - NX] = f2bf(wv[t - NX - 2 * NW]);
    else if (t < NX + 4 * NW) wob[t - NX - 3 * NW] = f2bf(wo[t - NX - 3 * NW]);
    else cbb[t - NX - 4 * NW] = f2bf(cb[t - NX - 4 * NW]);
  }
}

// ---------------- codebook norms (fp64 accumulate) ----------------
__global__ void c2_kernel(const float* __restrict__ cb, float* __restrict__ c2) {
  int i = blockIdx.x * blockDim.x + threadIdx.x;
  if (i >= HH * NC) return;
  const float* r = cb + (long)i * HDD;
  double s = 0.0;
  for (int j = 0; j < HDD; j++) s += (double)r[j] * (double)r[j];
  c2[i] = (float)s;
}

// ---------------- GEMM1: Q,V = x * W^T (bf16 MFMA), scatter epilogue ----------------
__global__ __launch_bounds__(256) void gemm_qv(
    const unsigned short* __restrict__ xb, const unsigned short* __restrict__ wb,
    unsigned short* __restrict__ qb, unsigned short* __restrict__ vt) {
  __shared__ __align__(16) unsigned short As[128 * 32];
  __shared__ __align__(16) unsigned short Bs[128 * 32];
  int tid = threadIdx.x;
  int wave = tid >> 6, lane = tid & 63;
  int quad = lane >> 4, col = lane & 15;
  int m0 = blockIdx.y * 128;
  int n0 = blockIdx.x * 128 + (blockIdx.x >= 8 ? 1024 : 0);
  f32x4 acc[4][4] = {};
  int row_in = (wave << 4) + (lane >> 2);
  int seg = lane & 3;
  const unsigned short* gA0 = xb + (long)(m0 + row_in) * DD + seg * 8;
  const unsigned short* gA1 = xb + (long)(m0 + 64 + row_in) * DD + seg * 8;
  const unsigned short* gB0 = wb + (long)(n0 + row_in) * DD + seg * 8;
  const unsigned short* gB1 = wb + (long)(n0 + 64 + row_in) * DD + seg * 8;
  unsigned short* lA0 = As + wave * 512;
  unsigned short* lA1 = As + 2048 + wave * 512;
  unsigned short* lB0 = Bs + wave * 512;
  unsigned short* lB1 = Bs + 2048 + wave * 512;
  int wm = wave & 1, wn = wave >> 1;
  const unsigned short* pa = As + (wm * 64 + col) * 32 + quad * 8;
  const unsigned short* pb = Bs + (wn * 64 + col) * 32 + quad * 8;
  for (int kk = 0; kk < DD; kk += 32) {
    __syncthreads();
    load_lds16(gA0 + kk, lA0);
    load_lds16(gA1 + kk, lA1);
    load_lds16(gB0 + kk, lB0);
    load_lds16(gB1 + kk, lB1);
    __syncthreads();
    bf16x8 af[4], bfr[4];
    for (int t = 0; t < 4; t++) af[t]  = *(const bf16x8*)(pa + t * 512);
    for (int t = 0; t < 4; t++) bfr[t] = *(const bf16x8*)(pb + t * 512);
    for (int mt = 0; mt < 4; mt++)
      for (int nt = 0; nt < 4; nt++)
        acc[mt][nt] = __builtin_amdgcn_mfma_f32_16x16x32_bf16(af[mt], bfr[nt], acc[mt][nt], 0, 0, 0);
  }
  for (int mt = 0; mt < 4; mt++)
    for (int nt = 0; nt < 4; nt++) {
      int mbase = m0 + wm * 64 + mt * 16 + quad * 4;
      int n = n0 + wn * 64 + nt * 16 + col;
      int which = n >> 10, e = n & 1023;
      int h = e >> 6, hd = e & 63;
      for (int r = 0; r < 4; r++) {
        int m = mbase + r;
        int b = m >> 11, l = m & 2047;
        unsigned short val = f2bf(acc[mt][nt][r]);
        long bh = (long)(b * HH + h);
        if (which == 0)      qb[(bh * LL + l) * HDD + hd] = val;
        else                 vt[(bh * HDD + hd) * LL + l] = val;
      }
    }
}

// ---------------- fp32 SGEMM: kf[m][e] = sum_d X[m][d] * Wk[e][d] ----------------
__global__ __launch_bounds__(256) void kgemm_f32(
    const float* __restrict__ X, const float* __restrict__ W,
    float* __restrict__ kf) {
  __shared__ float As[16][128];
  __shared__ float Bs[16][64];
  int tid = threadIdx.x;
  int n0 = blockIdx.x * 64;
  int m0 = blockIdx.y * 128;
  int am = tid >> 2;
  int ak4 = (tid & 3) * 4;
  int tn = tid & 15, tm = tid >> 4;
  float acc[8][4] = {};
  const float* pA0 = X + (long)(m0 + am) * DD + ak4;
  const float* pA1 = X + (long)(m0 + 64 + am) * DD + ak4;
  const float* pB  = W + (long)(n0 + am) * DD + ak4;
  float4 xa0 = *(const float4*)(pA0);
  float4 xa1 = *(const float4*)(pA1);
  float4 wb0 = *(const float4*)(pB);
  for (int k0 = 0; k0 < DD; k0 += 16) {
    __syncthreads();
#pragma unroll
    for (int j = 0; j < 4; j++) {
      As[ak4 + j][am]      = ((const float*)&xa0)[j];
      As[ak4 + j][64 + am] = ((const float*)&xa1)[j];
      Bs[ak4 + j][am]      = ((const float*)&wb0)[j];
    }
    __syncthreads();
    if (k0 + 16 < DD) {
      xa0 = *(const float4*)(pA0 + k0 + 16);
      xa1 = *(const float4*)(pA1 + k0 + 16);
      wb0 = *(const float4*)(pB + k0 + 16);
    }
#pragma unroll
    for (int k = 0; k < 16; k++) {
      float4 a0 = *(const float4*)&As[k][tm * 8];
      float4 a1 = *(const float4*)&As[k][tm * 8 + 4];
      float4 bv = *(const float4*)&Bs[k][tn * 4];
#pragma unroll
      for (int i = 0; i < 4; i++)
#pragma unroll
        for (int j = 0; j < 4; j++) {
          acc[i][j]     = fmaf(((const float*)&a0)[i], ((const float*)&bv)[j], acc[i][j]);
          acc[4 + i][j] = fmaf(((const float*)&a1)[i], ((const float*)&bv)[j], acc[4 + i][j]);
        }
    }
  }
  int h = n0 >> 6;
#pragma unroll
  for (int i = 0; i < 8; i++) {
    int m = m0 + tm * 8 + i;
    int b = m >> 11, l = m & 2047;
    float4 o;
    ((float*)&o)[0] = acc[i][0]; ((float*)&o)[1] = acc[i][1];
    ((float*)&o)[2] = acc[i][2]; ((float*)&o)[3] = acc[i][3];
    *(float4*)(kf + (((long)(b * HH + h) * LL + l) * HDD) + tn * 4) = o;
  }
}

// ---------------- fp32 VQ: 2 rows/thread, codes split across 4 waves, uniform code loads ----------------
__global__ __launch_bounds__(256) void vq_f32(
    const float* __restrict__ kf, const float* __restrict__ cb,
    const float* __restrict__ c2, const unsigned short* __restrict__ cbb,
    unsigned short* __restrict__ khat, float* __restrict__ scodes,
    float* __restrict__ lsum) {
  __shared__ float bv[4][2][64];
  __shared__ int   bix[4][2][64];
  int tid = threadIdx.x, lane = tid & 63;
  int w = tid >> 6;
  int blk = blockIdx.x;
  int bh = blk >> 4, rb = blk & 15;     // 16 chunks of 128 rows
  int h = bh & 15;
  int row0 = rb * 128 + lane;           // thread owns row0 and row0+64
  const float* kp0 = kf + ((long)bh * LL + row0) * HDD;
  const float* kp1 = kp0 + 64 * HDD;
  float kr0[64], kr1[64];
#pragma unroll
  for (int j = 0; j < 16; j++) {
    float4 t0 = *(const float4*)(kp0 + j * 4);
    float4 t1 = *(const float4*)(kp1 + j * 4);
    kr0[j * 4] = t0.x; kr0[j * 4 + 1] = t0.y; kr0[j * 4 + 2] = t0.z; kr0[j * 4 + 3] = t0.w;
    kr1[j * 4] = t1.x; kr1[j * 4 + 1] = t1.y; kr1[j * 4 + 2] = t1.z; kr1[j * 4 + 3] = t1.w;
  }
  const float* cbh = cb + (long)h * NC * HDD;
  const float* c2h = c2 + h * NC;
  int wbase = __builtin_amdgcn_readfirstlane(w << 7);   // uniform code-range base
  float best0 = 1e38f, best1 = 1e38f; int bi0 = 0, bi1 = 0;
  for (int i = 0; i < 128; i++) {
    int c = wbase + i;
    const float* cp = cbh + (long)c * HDD;
    float a0 = 0.f, a1 = 0.f, a2 = 0.f, a3 = 0.f;
    float e0 = 0.f, e1 = 0.f, e2 = 0.f, e3 = 0.f;
#pragma unroll
    for (int j = 0; j < 16; j++) {
      float4 cv = *(const float4*)(cp + j * 4);
      a0 = fmaf(kr0[4 * j],     cv.x, a0);
      a1 = fmaf(kr0[4 * j + 1], cv.y, a1);
      a2 = fmaf(kr0[4 * j + 2], cv.z, a2);
      a3 = fmaf(kr0[4 * j + 3], cv.w, a3);
      e0 = fmaf(kr1[4 * j],     cv.x, e0);
      e1 = fmaf(kr1[4 * j + 1], cv.y, e1);
      e2 = fmaf(kr1[4 * j + 2], cv.z, e2);
      e3 = fmaf(kr1[4 * j + 3], cv.w, e3);
    }
    float dot0 = (a0 + a1) + (a2 + a3);
    float dot1 = (e0 + e1) + (e2 + e3);
    float cc = c2h[c];
    float v0 = cc - 2.0f * dot0;
    float v1 = cc - 2.0f * dot1;
    if (v0 < best0) { best0 = v0; bi0 = c; }
    if (v1 < best1) { best1 = v1; bi1 = c; }
  }
  bv[w][0][lane] = best0; bix[w][0][lane] = bi0;
  bv[w][1][lane] = best1; bix[w][1][lane] = bi1;
  __syncthreads();
  if (tid < 64) {
    best0 = bv[0][0][lane]; bi0 = bix[0][0][lane];
    best1 = bv[0][1][lane]; bi1 = bix[0][1][lane];
#pragma unroll
    for (int ww = 1; ww < 4; ww++) {
      float v = bv[ww][0][lane]; int ii = bix[ww][0][lane];
      if (v < best0) { best0 = v; bi0 = ii; }
      v = bv[ww][1][lane]; ii = bix[ww][1][lane];
      if (v < best1) { best1 = v; bi1 = ii; }
    }
    float k20 = 0.f, k21 = 0.f;
#pragma unroll
    for (int j = 0; j < 64; j++) {
      k20 = fmaf(kr0[j], kr0[j], k20);
      k21 = fmaf(kr1[j], kr1[j], k21);
    }
    float part = (k20 + best0) + (k21 + best1);
    part += __shfl_xor(part, 1);  part += __shfl_xor(part, 2);
    part += __shfl_xor(part, 4);  part += __shfl_xor(part, 8);
    part += __shfl_xor(part, 16); part += __shfl_xor(part, 32);
    if (lane == 0) atomicAdd(lsum, part);
    scodes[(long)bh * LL + row0]      = (float)bi0;
    scodes[(long)bh * LL + row0 + 64] = (float)bi1;
    const unsigned short* cr0 = cbb + ((long)h * NC + bi0) * HDD;
    const unsigned short* cr1 = cbb + ((long)h * NC + bi1) * HDD;
    unsigned short* o0 = khat + ((long)bh * LL + row0) * HDD;
    unsigned short* o1 = o0 + 64 * HDD;
#pragma unroll
    for (int j = 0; j < 8; j++) {
      *(u16x8*)(o0 + j * 8) = *(const u16x8*)(cr0 + j * 8);
      *(u16x8*)(o1 + j * 8) = *(const u16x8*)(cr1 + j * 8);
    }
  }
}

// ---------------- flash attention: paired q-tiles (i, 31-i), no-max softmax ----------------
__global__ __launch_bounds__(256) void attn_kernel(
    const unsigned short* __restrict__ qb, const unsigned short* __restrict__ khat,
    const unsigned short* __restrict__ vt, unsigned short* __restrict__ attnb) {
  __shared__ __align__(16) unsigned short Pbuf[4][2][16 * 72];
  int tid = threadIdx.x, wave = tid >> 6, lane = tid & 63;
  int quad = lane >> 4, col = lane & 15;
  int pi = blockIdx.x;          // 0..15: pairs q-tile pi with 31-pi
  int bh = blockIdx.y;
  int b = bh >> 4, h = bh & 15;
  int ta = pi, tb = 31 - pi;    // ta < tb always
  int qbA = ta * 64 + wave * 16;
  int qbB = tb * 64 + wave * 16;
  const unsigned short* qrA = qb + ((long)bh * LL + qbA + col) * HDD;
  const unsigned short* qrB = qb + ((long)bh * LL + qbB + col) * HDD;
  bf16x8 aqA0 = *(const bf16x8*)(qrA + quad * 8);
  bf16x8 aqA1 = *(const bf16x8*)(qrA + 32 + quad * 8);
  bf16x8 aqB0 = *(const bf16x8*)(qrB + quad * 8);
  bf16x8 aqB1 = *(const bf16x8*)(qrB + 32 + quad * 8);
  float lA[4] = {0.f, 0.f, 0.f, 0.f}, lB[4] = {0.f, 0.f, 0.f, 0.f};
  f32x4 oA[4] = {}, oB[4] = {};
  unsigned short* PA = Pbuf[wave][0];
  unsigned short* PB = Pbuf[wave][1];
  const unsigned short* kh = khat + (long)bh * LL * HDD;
  const unsigned short* vh = vt + (long)bh * HDD * LL;
  const float SCL = 0.18033688011112042f;  // log2(e) / 8 -> exp2 softmax
  for (int kt = 0; kt <= tb; kt++) {
    int kbase = kt * 64;
    bool actA = (kt <= ta);
    f32x4 zA[4], zB[4];
    for (int nt = 0; nt < 4; nt++) {
      const unsigned short* krow = kh + (long)(kbase + nt * 16 + col) * HDD;
      bf16x8 k0 = *(const bf16x8*)(krow + quad * 8);
      bf16x8 k1 = *(const bf16x8*)(krow + 32 + quad * 8);
      f32x4 z = {};
      z = __builtin_amdgcn_mfma_f32_16x16x32_bf16(aqB0, k0, z, 0, 0, 0);
      z = __builtin_amdgcn_mfma_f32_16x16x32_bf16(aqB1, k1, z, 0, 0, 0);
      zB[nt] = z;
      if (actA) {
        f32x4 y = {};
        y = __builtin_amdgcn_mfma_f32_16x16x32_bf16(aqA0, k0, y, 0, 0, 0);
        y = __builtin_amdgcn_mfma_f32_16x16x32_bf16(aqA1, k1, y, 0, 0, 0);
        zA[nt] = y;
      }
    }
    for (int nt = 0; nt < 4; nt++) {
      int key = kbase + nt * 16 + col;
      for (int r = 0; r < 4; r++) {
        float sc = zB[nt][r] * SCL;
        if (kt == tb && key > qbB + quad * 4 + r) sc = -1e30f;
        float p = exp2f(sc);
        lB[r] += p;
        PB[(quad * 4 + r) * 72 + nt * 16 + col] = f2bf(p);
      }
    }
    if (actA) {
      for (int nt = 0; nt < 4; nt++) {
        int key = kbase + nt * 16 + col;
        for (int r = 0; r < 4; r++) {
          float sc = zA[nt][r] * SCL;
          if (kt == ta && key > qbA + quad * 4 + r) sc = -1e30f;
          float p = exp2f(sc);
          lA[r] += p;
          PA[(quad * 4 + r) * 72 + nt * 16 + col] = f2bf(p);
        }
      }
    }
    bf16x8 apB0 = *(const bf16x8*)(PB + col * 72 + quad * 8);
    bf16x8 apB1 = *(const bf16x8*)(PB + col * 72 + 32 + quad * 8);
    bf16x8 apA0, apA1;
    if (actA) {
      apA0 = *(const bf16x8*)(PA + col * 72 + quad * 8);
      apA1 = *(const bf16x8*)(PA + col * 72 + 32 + quad * 8);
    }
    for (int nt = 0; nt < 4; nt++) {
      const unsigned short* vrow = vh + (long)(nt * 16 + col) * LL + kbase;
      bf16x8 v0 = *(const bf16x8*)(vrow + quad * 8);
      bf16x8 v1 = *(const bf16x8*)(vrow + 32 + quad * 8);
      oB[nt] = __builtin_amdgcn_mfma_f32_16x16x32_bf16(apB0, v0, oB[nt], 0, 0, 0);
      oB[nt] = __builtin_amdgcn_mfma_f32_16x16x32_bf16(apB1, v1, oB[nt], 0, 0, 0);
      if (actA) {
        oA[nt] = __builtin_amdgcn_mfma_f32_16x16x32_bf16(apA0, v0, oA[nt], 0, 0, 0);
        oA[nt] = __builtin_amdgcn_mfma_f32_16x16x32_bf16(apA1, v1, oA[nt], 0, 0, 0);
      }
    }
  }
  // deferred row-sum reduction (16 lanes per row) + normalize + store
  float invA[4], invB[4];
  for (int r = 0; r < 4; r++) {
    float t = lA[r];
    t += __shfl_xor(t, 1); t += __shfl_xor(t, 2);
    t += __shfl_xor(t, 4); t += __shfl_xor(t, 8);
    invA[r] = 1.0f / t;
    float u = lB[r];
    u += __shfl_xor(u, 1); u += __shfl_xor(u, 2);
    u += __shfl_xor(u, 4); u += __shfl_xor(u, 8);
    invB[r] = 1.0f / u;
  }
  for (int r = 0; r < 4; r++) {
    int rowA = qbA + quad * 4 + r;
    int rowB = qbB + quad * 4 + r;
    for (int nt = 0; nt < 4; nt++) {
      int hd = nt * 16 + col;
      attnb[((long)b * LL + rowA) * DD + h * HDD + hd] = f2bf(oA[nt][r] * invA[r]);
      attnb[((long)b * LL + rowB) * DD + h * HDD + hd] = f2bf(oB[nt][r] * invB[r]);
    }
  }
}

// ---------------- GEMM2: out = attn * Wo^T (fp32 store) ----------------
__global__ __launch_bounds__(256) void gemm_out(
    const unsigned short* __restrict__ attnb, const unsigned short* __restrict__ wob,
    float* __restrict__ out) {
  __shared__ __align__(16) unsigned short As[128 * 32];
  __shared__ __align__(16) unsigned short Bs[128 * 32];
  int tid = threadIdx.x;
  int wave = tid >> 6, lane = tid & 63;
  int quad = lane >> 4, col = lane & 15;
  int m0 = blockIdx.y * 128;
  int n0 = blockIdx.x * 128;
  f32x4 acc[4][4] = {};
  int row_in = (wave << 4) + (lane >> 2);
  int seg = lane & 3;
  const unsigned short* gA0 = attnb + (long)(m0 + row_in) * DD + seg * 8;
  const unsigned short* gA1 = attnb + (long)(m0 + 64 + row_in) * DD + seg * 8;
  const unsigned short* gB0 = wob + (long)(n0 + row_in) * DD + seg * 8;
  const unsigned short* gB1 = wob + (long)(n0 + 64 + row_in) * DD + seg * 8;
  unsigned short* lA0 = As + wave * 512;
  unsigned short* lA1 = As + 2048 + wave * 512;
  unsigned short* lB0 = Bs + wave * 512;
  unsigned short* lB1 = Bs + 2048 + wave * 512;
  int wm = wave & 1, wn = wave >> 1;
  const unsigned short* pa = As + (wm * 64 + col) * 32 + quad * 8;
  const unsigned short* pb = Bs + (wn * 64 + col) * 32 + quad * 8;
  for (int kk = 0; kk < DD; kk += 32) {
    __syncthreads();
    load_lds16(gA0 + kk, lA0);
    load_lds16(gA1 + kk, lA1);
    load_lds16(gB0 + kk, lB0);
    load_lds16(gB1 + kk, lB1);
    __syncthreads();
    bf16x8 af[4], bfr[4];
    for (int t = 0; t < 4; t++) af[t]  = *(const bf16x8*)(pa + t * 512);
    for (int t = 0; t < 4; t++) bfr[t] = *(const bf16x8*)(pb + t * 512);
    for (int mt = 0; mt < 4; mt++)
      for (int nt = 0; nt < 4; nt++)
        acc[mt][nt] = __builtin_amdgcn_mfma_f32_16x16x32_bf16(af[mt], bfr[nt], acc[mt][nt], 0, 0, 0);
  }
  for (int mt = 0; mt < 4; mt++)
    for (int nt = 0; nt < 4; nt++) {
      int mbase = m0 + wm * 64 + mt * 16 + quad * 4;
      int n = n0 + wn * 64 + nt * 16 + col;
      for (int r = 0; r < 4; r++)
        out[(long)(mbase + r) * DD + n] = acc[mt][nt][r];
    }
}

// ---------------- finalize scalars ----------------
__global__ void finalize(const float* __restrict__ lsum, float* __restrict__ out) {
  if (threadIdx.x == 0) {
    float v = lsum[0] / (float)(BB * HH * LL);
    out[4194304] = v;
    out[4194305] = v;
  }
}

extern "C" void kernel_launch(void* const* d_in, const int* in_sizes, int n_in,
                              void* d_out, int out_size, void* d_ws, size_t ws_size,
                              hipStream_t stream) {
  const float* x  = (const float*)d_in[0];
  const float* wq = (const float*)d_in[1];
  const float* wk = (const float*)d_in[2];
  const float* wv = (const float*)d_in[3];
  const float* wo = (const float*)d_in[4];
  const float* cb = (const float*)d_in[5];
  float* out = (float*)d_out;

  char* ws = (char*)d_ws;
  size_t off = 0;
  auto alloc = [&](size_t bytes) {
    void* p = ws + off;
    off = (off + bytes + 255) & ~(size_t)255;
    return p;
  };
  unsigned short* xb    = (unsigned short*)alloc(4194304 * 2);
  unsigned short* wb    = (unsigned short*)alloc(3145728 * 2);
  unsigned short* wob   = (unsigned short*)alloc(1048576 * 2);
  unsigned short* cbb   = (unsigned short*)alloc(524288 * 2);
  unsigned short* qb    = (unsigned short*)alloc(4194304 * 2);
  unsigned short* vt    = (unsigned short*)alloc(4194304 * 2);
  unsigned short* khat  = (unsigned short*)alloc(4194304 * 2);
  unsigned short* attnb = (unsigned short*)alloc(4194304 * 2);
  float* kf   = (float*)alloc(4194304 * 4);
  float* c2   = (float*)alloc(8192 * 4);
  float* lsum = (float*)alloc(256);

  cast_all<<<dim3(4096), dim3(256), 0, stream>>>(x, wq, wk, wv, wo, cb, xb, wb, wob, cbb, lsum);
  c2_kernel<<<dim3(32), dim3(256), 0, stream>>>(cb, c2);
  gemm_qv<<<dim3(16, 32), dim3(256), 0, stream>>>(xb, wb, qb, vt);
  kgemm_f32<<<dim3(16, 32), dim3(256), 0, stream>>>(x, wk, kf);
  vq_f32<<<dim3(512), dim3(256), 0, stream>>>(kf, cb, c2, cbb, khat, out + 4194306, lsum);
  attn_kernel<<<dim3(16, 32), dim3(256), 0, stream>>>(qb, khat, vt, attnb);
  gemm_out<<<dim3(8, 32), dim3(256), 0, stream>>>(attnb, wob, out);
  finalize<<<dim3(1), dim3(64), 0, stream>>>(lsum, out);
}

// Round 5
// 521.098 us; speedup vs baseline: 1.4842x; 1.1028x over previous
//
#include <hip/hip_runtime.h>
#include <stdint.h>

#define BB 2
#define HH 16
#define LL 2048
#define DD 1024
#define HDD 64
#define NC 512

typedef __bf16 bf16x8 __attribute__((ext_vector_type(8)));
typedef float f32x4 __attribute__((ext_vector_type(4)));
typedef unsigned short u16x8 __attribute__((ext_vector_type(8)));

__device__ __forceinline__ unsigned short f2bf(float f) {
  union { float f; unsigned u; } v; v.f = f;
  unsigned u = v.u;
  u += 0x7fffu + ((u >> 16) & 1u);
  return (unsigned short)(u >> 16);
}
__device__ __forceinline__ float bf2f(unsigned short h) {
  union { unsigned u; float f; } v; v.u = ((unsigned)h) << 16;
  return v.f;
}

// async global->LDS, 16B per lane; lds ptr must be wave-uniform base (HW adds lane*16)
__device__ __forceinline__ void load_lds16(const unsigned short* g, unsigned short* l) {
  __builtin_amdgcn_global_load_lds((const __attribute__((address_space(1))) void*)g,
                                   (__attribute__((address_space(3))) void*)l, 16, 0, 0);
}

// ---------------- cast kernel ----------------
__global__ void cast_all(const float* __restrict__ x, const float* __restrict__ wq,
                         const float* __restrict__ wk, const float* __restrict__ wv,
                         const float* __restrict__ wo, const float* __restrict__ cb,
                         unsigned short* __restrict__ xb, unsigned short* __restrict__ wb,
                         unsigned short* __restrict__ wob, unsigned short* __restrict__ cbb,
                         float* __restrict__ lsum) {
  long i = (long)blockIdx.x * blockDim.x + threadIdx.x;
  if (i == 0) lsum[0] = 0.f;
  const long NX = 4194304, NW = 1048576, NCB = 524288;
  const long TOT = NX + 4 * NW + NCB;
  for (long t = i; t < TOT; t += (long)gridDim.x * blockDim.x) {
    if (t < NX) xb[t] = f2bf(x[t]);
    else if (t < NX + NW) wb[t - NX] = f2bf(wq[t - NX]);
    else if (t < NX + 2 * NW) wb[t - NX] = f2bf(wk[t - NX - NW]);
    else if (t < NX + 3 * NW) wb[t - NX] = f2bf(wv[t - NX - 2 * NW]);
    else if (t < NX + 4 * NW) wob[t - NX - 3 * NW] = f2bf(wo[t - NX - 3 * NW]);
    else cbb[t - NX - 4 * NW] = f2bf(cb[t - NX - 4 * NW]);
  }
}

// ---------------- codebook norms (fp64 accumulate) ----------------
__global__ void c2_kernel(const float* __restrict__ cb, float* __restrict__ c2) {
  int i = blockIdx.x * blockDim.x + threadIdx.x;
  if (i >= HH * NC) return;
  const float* r = cb + (long)i * HDD;
  double s = 0.0;
  for (int j = 0; j < HDD; j++) s += (double)r[j] * (double)r[j];
  c2[i] = (float)s;
}

// ---------------- GEMM1: Q,V = x * W^T (bf16 MFMA), scatter epilogue ----------------
__global__ __launch_bounds__(256) void gemm_qv(
    const unsigned short* __restrict__ xb, const unsigned short* __restrict__ wb,
    unsigned short* __restrict__ qb, unsigned short* __restrict__ vt) {
  __shared__ __align__(16) unsigned short As[128 * 32];
  __shared__ __align__(16) unsigned short Bs[128 * 32];
  int tid = threadIdx.x;
  int wave = tid >> 6, lane = tid & 63;
  int quad = lane >> 4, col = lane & 15;
  int m0 = blockIdx.y * 128;
  int n0 = blockIdx.x * 128 + (blockIdx.x >= 8 ? 1024 : 0);
  f32x4 acc[4][4] = {};
  int row_in = (wave << 4) + (lane >> 2);
  int seg = lane & 3;
  const unsigned short* gA0 = xb + (long)(m0 + row_in) * DD + seg * 8;
  const unsigned short* gA1 = xb + (long)(m0 + 64 + row_in) * DD + seg * 8;
  const unsigned short* gB0 = wb + (long)(n0 + row_in) * DD + seg * 8;
  const unsigned short* gB1 = wb + (long)(n0 + 64 + row_in) * DD + seg * 8;
  unsigned short* lA0 = As + wave * 512;
  unsigned short* lA1 = As + 2048 + wave * 512;
  unsigned short* lB0 = Bs + wave * 512;
  unsigned short* lB1 = Bs + 2048 + wave * 512;
  int wm = wave & 1, wn = wave >> 1;
  const unsigned short* pa = As + (wm * 64 + col) * 32 + quad * 8;
  const unsigned short* pb = Bs + (wn * 64 + col) * 32 + quad * 8;
  for (int kk = 0; kk < DD; kk += 32) {
    __syncthreads();
    load_lds16(gA0 + kk, lA0);
    load_lds16(gA1 + kk, lA1);
    load_lds16(gB0 + kk, lB0);
    load_lds16(gB1 + kk, lB1);
    __syncthreads();
    bf16x8 af[4], bfr[4];
    for (int t = 0; t < 4; t++) af[t]  = *(const bf16x8*)(pa + t * 512);
    for (int t = 0; t < 4; t++) bfr[t] = *(const bf16x8*)(pb + t * 512);
    for (int mt = 0; mt < 4; mt++)
      for (int nt = 0; nt < 4; nt++)
        acc[mt][nt] = __builtin_amdgcn_mfma_f32_16x16x32_bf16(af[mt], bfr[nt], acc[mt][nt], 0, 0, 0);
  }
  for (int mt = 0; mt < 4; mt++)
    for (int nt = 0; nt < 4; nt++) {
      int mbase = m0 + wm * 64 + mt * 16 + quad * 4;
      int n = n0 + wn * 64 + nt * 16 + col;
      int which = n >> 10, e = n & 1023;
      int h = e >> 6, hd = e & 63;
      for (int r = 0; r < 4; r++) {
        int m = mbase + r;
        int b = m >> 11, l = m & 2047;
        unsigned short val = f2bf(acc[mt][nt][r]);
        long bh = (long)(b * HH + h);
        if (which == 0)      qb[(bh * LL + l) * HDD + hd] = val;
        else                 vt[(bh * HDD + hd) * LL + l] = val;
      }
    }
}

// ---------------- fp32 SGEMM: kf[m][e] = sum_d X[m][d] * Wk[e][d] ----------------
__global__ __launch_bounds__(256) void kgemm_f32(
    const float* __restrict__ X, const float* __restrict__ W,
    float* __restrict__ kf) {
  __shared__ float As[16][128];
  __shared__ float Bs[16][64];
  int tid = threadIdx.x;
  int n0 = blockIdx.x * 64;
  int m0 = blockIdx.y * 128;
  int am = tid >> 2;
  int ak4 = (tid & 3) * 4;
  int tn = tid & 15, tm = tid >> 4;
  float acc[8][4] = {};
  const float* pA0 = X + (long)(m0 + am) * DD + ak4;
  const float* pA1 = X + (long)(m0 + 64 + am) * DD + ak4;
  const float* pB  = W + (long)(n0 + am) * DD + ak4;
  float4 xa0 = *(const float4*)(pA0);
  float4 xa1 = *(const float4*)(pA1);
  float4 wb0 = *(const float4*)(pB);
  for (int k0 = 0; k0 < DD; k0 += 16) {
    __syncthreads();
#pragma unroll
    for (int j = 0; j < 4; j++) {
      As[ak4 + j][am]      = ((const float*)&xa0)[j];
      As[ak4 + j][64 + am] = ((const float*)&xa1)[j];
      Bs[ak4 + j][am]      = ((const float*)&wb0)[j];
    }
    __syncthreads();
    if (k0 + 16 < DD) {
      xa0 = *(const float4*)(pA0 + k0 + 16);
      xa1 = *(const float4*)(pA1 + k0 + 16);
      wb0 = *(const float4*)(pB + k0 + 16);
    }
#pragma unroll
    for (int k = 0; k < 16; k++) {
      float4 a0 = *(const float4*)&As[k][tm * 8];
      float4 a1 = *(const float4*)&As[k][tm * 8 + 4];
      float4 bv = *(const float4*)&Bs[k][tn * 4];
#pragma unroll
      for (int i = 0; i < 4; i++)
#pragma unroll
        for (int j = 0; j < 4; j++) {
          acc[i][j]     = fmaf(((const float*)&a0)[i], ((const float*)&bv)[j], acc[i][j]);
          acc[4 + i][j] = fmaf(((const float*)&a1)[i], ((const float*)&bv)[j], acc[4 + i][j]);
        }
    }
  }
  int h = n0 >> 6;
#pragma unroll
  for (int i = 0; i < 8; i++) {
    int m = m0 + tm * 8 + i;
    int b = m >> 11, l = m & 2047;
    float4 o;
    ((float*)&o)[0] = acc[i][0]; ((float*)&o)[1] = acc[i][1];
    ((float*)&o)[2] = acc[i][2]; ((float*)&o)[3] = acc[i][3];
    *(float4*)(kf + (((long)(b * HH + h) * LL + l) * HDD) + tn * 4) = o;
  }
}

// ---------------- fp32 VQ: LDS-staged codes, double-buffered; 64 rows/block, 4-way code split ----------------
__global__ __launch_bounds__(256) void vq_f32(
    const float* __restrict__ kf, const float* __restrict__ cb,
    const float* __restrict__ c2, const unsigned short* __restrict__ cbb,
    unsigned short* __restrict__ khat, float* __restrict__ scodes,
    float* __restrict__ lsum) {
  __shared__ __align__(16) float codes[2][32 * 64];   // 16 KB double-buffered
  __shared__ float c2s[2][32];
  __shared__ float bvs[4][64];
  __shared__ int   bis[4][64];
  __shared__ int   finalIdx[64];
  int tid = threadIdx.x, lane = tid & 63, w = tid >> 6;
  int blk = blockIdx.x;
  int bh = blk >> 5, rb = blk & 31;     // 32 chunks of 64 rows per bh
  int h = bh & 15;
  int row = rb * 64 + lane;
  const float* kp = kf + ((long)bh * LL + row) * HDD;
  float kr[64];
#pragma unroll
  for (int j = 0; j < 16; j++) {
    float4 t = *(const float4*)(kp + j * 4);
    kr[j * 4] = t.x; kr[j * 4 + 1] = t.y; kr[j * 4 + 2] = t.z; kr[j * 4 + 3] = t.w;
  }
  const float* cbh = cb + (long)h * NC * HDD;
  const float* c2h = c2 + h * NC;
  int sc_code = tid >> 3;               // 0..31
  int sc_part = (tid & 7) * 8;          // 0..56
  // prologue: stage chunk 0
  {
    const float* src = cbh + (long)sc_code * HDD + sc_part;
    float4 s0 = *(const float4*)(src);
    float4 s1 = *(const float4*)(src + 4);
    *(float4*)&codes[0][sc_code * 64 + sc_part] = s0;
    *(float4*)&codes[0][sc_code * 64 + sc_part + 4] = s1;
    if (tid < 32) c2s[0][tid] = c2h[tid];
  }
  __syncthreads();
  float best = 1e38f; int bidx = 0;
  for (int ch = 0; ch < 16; ch++) {
    int buf = ch & 1;
    if (ch + 1 < 16) {
      const float* src = cbh + (long)((ch + 1) * 32 + sc_code) * HDD + sc_part;
      float4 s0 = *(const float4*)(src);
      float4 s1 = *(const float4*)(src + 4);
      *(float4*)&codes[buf ^ 1][sc_code * 64 + sc_part] = s0;
      *(float4*)&codes[buf ^ 1][sc_code * 64 + sc_part + 4] = s1;
      if (tid < 32) c2s[buf ^ 1][tid] = c2h[(ch + 1) * 32 + tid];
    }
#pragma unroll
    for (int i = 0; i < 8; i++) {
      int ci = w * 8 + i;                         // code within chunk
      const float* cp = &codes[buf][ci * 64];
      float a0 = 0.f, a1 = 0.f, a2 = 0.f, a3 = 0.f;
#pragma unroll
      for (int j = 0; j < 16; j++) {
        float4 cv = *(const float4*)(cp + j * 4);
        a0 = fmaf(kr[4 * j],     cv.x, a0);
        a1 = fmaf(kr[4 * j + 1], cv.y, a1);
        a2 = fmaf(kr[4 * j + 2], cv.z, a2);
        a3 = fmaf(kr[4 * j + 3], cv.w, a3);
      }
      float dot = (a0 + a1) + (a2 + a3);
      float val = c2s[buf][ci] - 2.0f * dot;
      int c = ch * 32 + ci;
      if (val < best) { best = val; bidx = c; }   // per-wave codes ascend -> first occurrence
    }
    __syncthreads();
  }
  bvs[w][lane] = best; bis[w][lane] = bidx;
  __syncthreads();
  if (tid < 64) {
#pragma unroll
    for (int ww = 1; ww < 4; ww++) {
      float v = bvs[ww][lane]; int ii = bis[ww][lane];
      if (v < best || (v == best && ii < bidx)) { best = v; bidx = ii; }
    }
    float k2 = 0.f;
#pragma unroll
    for (int j = 0; j < 64; j++) k2 = fmaf(kr[j], kr[j], k2);
    float part = k2 + best;
    part += __shfl_xor(part, 1);  part += __shfl_xor(part, 2);
    part += __shfl_xor(part, 4);  part += __shfl_xor(part, 8);
    part += __shfl_xor(part, 16); part += __shfl_xor(part, 32);
    if (lane == 0) atomicAdd(lsum, part);
    scodes[(long)bh * LL + row] = (float)bidx;
    finalIdx[lane] = bidx;
  }
  __syncthreads();
  // cooperative khat gather: thread t -> row t>>2, 16-elem segment (t&3)
  {
    int r = tid >> 2, p = (tid & 3) * 16;
    int code = finalIdx[r];
    const unsigned short* src = cbb + ((long)h * NC + code) * HDD + p;
    unsigned short* dst = khat + ((long)bh * LL + rb * 64 + r) * HDD + p;
    *(u16x8*)(dst)     = *(const u16x8*)(src);
    *(u16x8*)(dst + 8) = *(const u16x8*)(src + 8);
  }
}

// ---------------- flash attention: paired q-tiles (i, 31-i), no-max softmax ----------------
__global__ __launch_bounds__(256) void attn_kernel(
    const unsigned short* __restrict__ qb, const unsigned short* __restrict__ khat,
    const unsigned short* __restrict__ vt, unsigned short* __restrict__ attnb) {
  __shared__ __align__(16) unsigned short Pbuf[4][2][16 * 72];
  int tid = threadIdx.x, wave = tid >> 6, lane = tid & 63;
  int quad = lane >> 4, col = lane & 15;
  int pi = blockIdx.x;          // 0..15: pairs q-tile pi with 31-pi
  int bh = blockIdx.y;
  int b = bh >> 4, h = bh & 15;
  int ta = pi, tb = 31 - pi;    // ta < tb always
  int qbA = ta * 64 + wave * 16;
  int qbB = tb * 64 + wave * 16;
  const unsigned short* qrA = qb + ((long)bh * LL + qbA + col) * HDD;
  const unsigned short* qrB = qb + ((long)bh * LL + qbB + col) * HDD;
  bf16x8 aqA0 = *(const bf16x8*)(qrA + quad * 8);
  bf16x8 aqA1 = *(const bf16x8*)(qrA + 32 + quad * 8);
  bf16x8 aqB0 = *(const bf16x8*)(qrB + quad * 8);
  bf16x8 aqB1 = *(const bf16x8*)(qrB + 32 + quad * 8);
  float lA[4] = {0.f, 0.f, 0.f, 0.f}, lB[4] = {0.f, 0.f, 0.f, 0.f};
  f32x4 oA[4] = {}, oB[4] = {};
  unsigned short* PA = Pbuf[wave][0];
  unsigned short* PB = Pbuf[wave][1];
  const unsigned short* kh = khat + (long)bh * LL * HDD;
  const unsigned short* vh = vt + (long)bh * HDD * LL;
  const float SCL = 0.18033688011112042f;  // log2(e) / 8 -> exp2 softmax
  for (int kt = 0; kt <= tb; kt++) {
    int kbase = kt * 64;
    bool actA = (kt <= ta);
    f32x4 zA[4], zB[4];
    for (int nt = 0; nt < 4; nt++) {
      const unsigned short* krow = kh + (long)(kbase + nt * 16 + col) * HDD;
      bf16x8 k0 = *(const bf16x8*)(krow + quad * 8);
      bf16x8 k1 = *(const bf16x8*)(krow + 32 + quad * 8);
      f32x4 z = {};
      z = __builtin_amdgcn_mfma_f32_16x16x32_bf16(aqB0, k0, z, 0, 0, 0);
      z = __builtin_amdgcn_mfma_f32_16x16x32_bf16(aqB1, k1, z, 0, 0, 0);
      zB[nt] = z;
      if (actA) {
        f32x4 y = {};
        y = __builtin_amdgcn_mfma_f32_16x16x32_bf16(aqA0, k0, y, 0, 0, 0);
        y = __builtin_amdgcn_mfma_f32_16x16x32_bf16(aqA1, k1, y, 0, 0, 0);
        zA[nt] = y;
      }
    }
    for (int nt = 0; nt < 4; nt++) {
      int key = kbase + nt * 16 + col;
      for (int r = 0; r < 4; r++) {
        float sc = zB[nt][r] * SCL;
        if (kt == tb && key > qbB + quad * 4 + r) sc = -1e30f;
        float p = exp2f(sc);
        lB[r] += p;
        PB[(quad * 4 + r) * 72 + nt * 16 + col] = f2bf(p);
      }
    }
    if (actA) {
      for (int nt = 0; nt < 4; nt++) {
        int key = kbase + nt * 16 + col;
        for (int r = 0; r < 4; r++) {
          float sc = zA[nt][r] * SCL;
          if (kt == ta && key > qbA + quad * 4 + r) sc = -1e30f;
          float p = exp2f(sc);
          lA[r] += p;
          PA[(quad * 4 + r) * 72 + nt * 16 + col] = f2bf(p);
        }
      }
    }
    bf16x8 apB0 = *(const bf16x8*)(PB + col * 72 + quad * 8);
    bf16x8 apB1 = *(const bf16x8*)(PB + col * 72 + 32 + quad * 8);
    bf16x8 apA0, apA1;
    if (actA) {
      apA0 = *(const bf16x8*)(PA + col * 72 + quad * 8);
      apA1 = *(const bf16x8*)(PA + col * 72 + 32 + quad * 8);
    }
    for (int nt = 0; nt < 4; nt++) {
      const unsigned short* vrow = vh + (long)(nt * 16 + col) * LL + kbase;
      bf16x8 v0 = *(const bf16x8*)(vrow + quad * 8);
      bf16x8 v1 = *(const bf16x8*)(vrow + 32 + quad * 8);
      oB[nt] = __builtin_amdgcn_mfma_f32_16x16x32_bf16(apB0, v0, oB[nt], 0, 0, 0);
      oB[nt] = __builtin_amdgcn_mfma_f32_16x16x32_bf16(apB1, v1, oB[nt], 0, 0, 0);
      if (actA) {
        oA[nt] = __builtin_amdgcn_mfma_f32_16x16x32_bf16(apA0, v0, oA[nt], 0, 0, 0);
        oA[nt] = __builtin_amdgcn_mfma_f32_16x16x32_bf16(apA1, v1, oA[nt], 0, 0, 0);
      }
    }
  }
  float invA[4], invB[4];
  for (int r = 0; r < 4; r++) {
    float t = lA[r];
    t += __shfl_xor(t, 1); t += __shfl_xor(t, 2);
    t += __shfl_xor(t, 4); t += __shfl_xor(t, 8);
    invA[r] = 1.0f / t;
    float u = lB[r];
    u += __shfl_xor(u, 1); u += __shfl_xor(u, 2);
    u += __shfl_xor(u, 4); u += __shfl_xor(u, 8);
    invB[r] = 1.0f / u;
  }
  for (int r = 0; r < 4; r++) {
    int rowA = qbA + quad * 4 + r;
    int rowB = qbB + quad * 4 + r;
    for (int nt = 0; nt < 4; nt++) {
      int hd = nt * 16 + col;
      attnb[((long)b * LL + rowA) * DD + h * HDD + hd] = f2bf(oA[nt][r] * invA[r]);
      attnb[((long)b * LL + rowB) * DD + h * HDD + hd] = f2bf(oB[nt][r] * invB[r]);
    }
  }
}

// ---------------- GEMM2: out = attn * Wo^T (fp32 store) ----------------
__global__ __launch_bounds__(256) void gemm_out(
    const unsigned short* __restrict__ attnb, const unsigned short* __restrict__ wob,
    float* __restrict__ out) {
  __shared__ __align__(16) unsigned short As[128 * 32];
  __shared__ __align__(16) unsigned short Bs[128 * 32];
  int tid = threadIdx.x;
  int wave = tid >> 6, lane = tid & 63;
  int quad = lane >> 4, col = lane & 15;
  int m0 = blockIdx.y * 128;
  int n0 = blockIdx.x * 128;
  f32x4 acc[4][4] = {};
  int row_in = (wave << 4) + (lane >> 2);
  int seg = lane & 3;
  const unsigned short* gA0 = attnb + (long)(m0 + row_in) * DD + seg * 8;
  const unsigned short* gA1 = attnb + (long)(m0 + 64 + row_in) * DD + seg * 8;
  const unsigned short* gB0 = wob + (long)(n0 + row_in) * DD + seg * 8;
  const unsigned short* gB1 = wob + (long)(n0 + 64 + row_in) * DD + seg * 8;
  unsigned short* lA0 = As + wave * 512;
  unsigned short* lA1 = As + 2048 + wave * 512;
  unsigned short* lB0 = Bs + wave * 512;
  unsigned short* lB1 = Bs + 2048 + wave * 512;
  int wm = wave & 1, wn = wave >> 1;
  const unsigned short* pa = As + (wm * 64 + col) * 32 + quad * 8;
  const unsigned short* pb = Bs + (wn * 64 + col) * 32 + quad * 8;
  for (int kk = 0; kk < DD; kk += 32) {
    __syncthreads();
    load_lds16(gA0 + kk, lA0);
    load_lds16(gA1 + kk, lA1);
    load_lds16(gB0 + kk, lB0);
    load_lds16(gB1 + kk, lB1);
    __syncthreads();
    bf16x8 af[4], bfr[4];
    for (int t = 0; t < 4; t++) af[t]  = *(const bf16x8*)(pa + t * 512);
    for (int t = 0; t < 4; t++) bfr[t] = *(const bf16x8*)(pb + t * 512);
    for (int mt = 0; mt < 4; mt++)
      for (int nt = 0; nt < 4; nt++)
        acc[mt][nt] = __builtin_amdgcn_mfma_f32_16x16x32_bf16(af[mt], bfr[nt], acc[mt][nt], 0, 0, 0);
  }
  for (int mt = 0; mt < 4; mt++)
    for (int nt = 0; nt < 4; nt++) {
      int mbase = m0 + wm * 64 + mt * 16 + quad * 4;
      int n = n0 + wn * 64 + nt * 16 + col;
      for (int r = 0; r < 4; r++)
        out[(long)(mbase + r) * DD + n] = acc[mt][nt][r];
    }
}

// ---------------- finalize scalars ----------------
__global__ void finalize(const float* __restrict__ lsum, float* __restrict__ out) {
  if (threadIdx.x == 0) {
    float v = lsum[0] / (float)(BB * HH * LL);
    out[4194304] = v;
    out[4194305] = v;
  }
}

extern "C" void kernel_launch(void* const* d_in, const int* in_sizes, int n_in,
                              void* d_out, int out_size, void* d_ws, size_t ws_size,
                              hipStream_t stream) {
  const float* x  = (const float*)d_in[0];
  const float* wq = (const float*)d_in[1];
  const float* wk = (const float*)d_in[2];
  const float* wv = (const float*)d_in[3];
  const float* wo = (const float*)d_in[4];
  const float* cb = (const float*)d_in[5];
  float* out = (float*)d_out;

  char* ws = (char*)d_ws;
  size_t off = 0;
  auto alloc = [&](size_t bytes) {
    void* p = ws + off;
    off = (off + bytes + 255) & ~(size_t)255;
    return p;
  };
  unsigned short* xb    = (unsigned short*)alloc(4194304 * 2);
  unsigned short* wb    = (unsigned short*)alloc(3145728 * 2);
  unsigned short* wob   = (unsigned short*)alloc(1048576 * 2);
  unsigned short* cbb   = (unsigned short*)alloc(524288 * 2);
  unsigned short* qb    = (unsigned short*)alloc(4194304 * 2);
  unsigned short* vt    = (unsigned short*)alloc(4194304 * 2);
  unsigned short* khat  = (unsigned short*)alloc(4194304 * 2);
  unsigned short* attnb = (unsigned short*)alloc(4194304 * 2);
  float* kf   = (float*)alloc(4194304 * 4);
  float* c2   = (float*)alloc(8192 * 4);
  float* lsum = (float*)alloc(256);

  cast_all<<<dim3(4096), dim3(256), 0, stream>>>(x, wq, wk, wv, wo, cb, xb, wb, wob, cbb, lsum);
  c2_kernel<<<dim3(32), dim3(256), 0, stream>>>(cb, c2);
  gemm_qv<<<dim3(16, 32), dim3(256), 0, stream>>>(xb, wb, qb, vt);
  kgemm_f32<<<dim3(16, 32), dim3(256), 0, stream>>>(x, wk, kf);
  vq_f32<<<dim3(1024), dim3(256), 0, stream>>>(kf, cb, c2, cbb, khat, out + 4194306, lsum);
  attn_kernel<<<dim3(16, 32), dim3(256), 0, stream>>>(qb, khat, vt, attnb);
  gemm_out<<<dim3(8, 32), dim3(256), 0, stream>>>(attnb, wob, out);
  finalize<<<dim3(1), dim3(64), 0, stream>>>(lsum, out);
}

// Round 6
// 507.454 us; speedup vs baseline: 1.5241x; 1.0269x over previous
//
#include <hip/hip_runtime.h>
#include <stdint.h>

#define BB 2
#define HH 16
#define LL 2048
#define DD 1024
#define HDD 64
#define NC 512

typedef __bf16 bf16x8 __attribute__((ext_vector_type(8)));
typedef float f32x4 __attribute__((ext_vector_type(4)));
typedef unsigned short u16x8 __attribute__((ext_vector_type(8)));

__device__ __forceinline__ unsigned short f2bf(float f) {
  union { float f; unsigned u; } v; v.f = f;
  unsigned u = v.u;
  u += 0x7fffu + ((u >> 16) & 1u);
  return (unsigned short)(u >> 16);
}
__device__ __forceinline__ float bf2f(unsigned short h) {
  union { unsigned u; float f; } v; v.u = ((unsigned)h) << 16;
  return v.f;
}

// async global->LDS, 16B per lane; lds ptr must be wave-uniform base (HW adds lane*16)
__device__ __forceinline__ void load_lds16(const unsigned short* g, unsigned short* l) {
  __builtin_amdgcn_global_load_lds((const __attribute__((address_space(1))) void*)g,
                                   (__attribute__((address_space(3))) void*)l, 16, 0, 0);
}

// ---------------- cast kernel (adds codebook lo-split) ----------------
__global__ void cast_all(const float* __restrict__ x, const float* __restrict__ wq,
                         const float* __restrict__ wk, const float* __restrict__ wv,
                         const float* __restrict__ wo, const float* __restrict__ cb,
                         unsigned short* __restrict__ xb, unsigned short* __restrict__ wb,
                         unsigned short* __restrict__ wob, unsigned short* __restrict__ cbb,
                         unsigned short* __restrict__ cbl, float* __restrict__ lsum) {
  long i = (long)blockIdx.x * blockDim.x + threadIdx.x;
  if (i == 0) lsum[0] = 0.f;
  const long NX = 4194304, NW = 1048576, NCB = 524288;
  const long TOT = NX + 4 * NW + NCB;
  for (long t = i; t < TOT; t += (long)gridDim.x * blockDim.x) {
    if (t < NX) xb[t] = f2bf(x[t]);
    else if (t < NX + NW) wb[t - NX] = f2bf(wq[t - NX]);
    else if (t < NX + 2 * NW) wb[t - NX] = f2bf(wk[t - NX - NW]);
    else if (t < NX + 3 * NW) wb[t - NX] = f2bf(wv[t - NX - 2 * NW]);
    else if (t < NX + 4 * NW) wob[t - NX - 3 * NW] = f2bf(wo[t - NX - 3 * NW]);
    else {
      long idx = t - NX - 4 * NW;
      float v = cb[idx];
      unsigned short hi = f2bf(v);
      cbb[idx] = hi;
      cbl[idx] = f2bf(v - bf2f(hi));
    }
  }
}

// ---------------- codebook norms (fp64 accumulate) ----------------
__global__ void c2_kernel(const float* __restrict__ cb, float* __restrict__ c2) {
  int i = blockIdx.x * blockDim.x + threadIdx.x;
  if (i >= HH * NC) return;
  const float* r = cb + (long)i * HDD;
  double s = 0.0;
  for (int j = 0; j < HDD; j++) s += (double)r[j] * (double)r[j];
  c2[i] = (float)s;
}

// ---------------- GEMM1: Q,V = x * W^T (bf16 MFMA), scatter epilogue ----------------
__global__ __launch_bounds__(256) void gemm_qv(
    const unsigned short* __restrict__ xb, const unsigned short* __restrict__ wb,
    unsigned short* __restrict__ qb, unsigned short* __restrict__ vt) {
  __shared__ __align__(16) unsigned short As[128 * 32];
  __shared__ __align__(16) unsigned short Bs[128 * 32];
  int tid = threadIdx.x;
  int wave = tid >> 6, lane = tid & 63;
  int quad = lane >> 4, col = lane & 15;
  int m0 = blockIdx.y * 128;
  int n0 = blockIdx.x * 128 + (blockIdx.x >= 8 ? 1024 : 0);
  f32x4 acc[4][4] = {};
  int row_in = (wave << 4) + (lane >> 2);
  int seg = lane & 3;
  const unsigned short* gA0 = xb + (long)(m0 + row_in) * DD + seg * 8;
  const unsigned short* gA1 = xb + (long)(m0 + 64 + row_in) * DD + seg * 8;
  const unsigned short* gB0 = wb + (long)(n0 + row_in) * DD + seg * 8;
  const unsigned short* gB1 = wb + (long)(n0 + 64 + row_in) * DD + seg * 8;
  unsigned short* lA0 = As + wave * 512;
  unsigned short* lA1 = As + 2048 + wave * 512;
  unsigned short* lB0 = Bs + wave * 512;
  unsigned short* lB1 = Bs + 2048 + wave * 512;
  int wm = wave & 1, wn = wave >> 1;
  const unsigned short* pa = As + (wm * 64 + col) * 32 + quad * 8;
  const unsigned short* pb = Bs + (wn * 64 + col) * 32 + quad * 8;
  for (int kk = 0; kk < DD; kk += 32) {
    __syncthreads();
    load_lds16(gA0 + kk, lA0);
    load_lds16(gA1 + kk, lA1);
    load_lds16(gB0 + kk, lB0);
    load_lds16(gB1 + kk, lB1);
    __syncthreads();
    bf16x8 af[4], bfr[4];
    for (int t = 0; t < 4; t++) af[t]  = *(const bf16x8*)(pa + t * 512);
    for (int t = 0; t < 4; t++) bfr[t] = *(const bf16x8*)(pb + t * 512);
    for (int mt = 0; mt < 4; mt++)
      for (int nt = 0; nt < 4; nt++)
        acc[mt][nt] = __builtin_amdgcn_mfma_f32_16x16x32_bf16(af[mt], bfr[nt], acc[mt][nt], 0, 0, 0);
  }
  for (int mt = 0; mt < 4; mt++)
    for (int nt = 0; nt < 4; nt++) {
      int mbase = m0 + wm * 64 + mt * 16 + quad * 4;
      int n = n0 + wn * 64 + nt * 16 + col;
      int which = n >> 10, e = n & 1023;
      int h = e >> 6, hd = e & 63;
      for (int r = 0; r < 4; r++) {
        int m = mbase + r;
        int b = m >> 11, l = m & 2047;
        unsigned short val = f2bf(acc[mt][nt][r]);
        long bh = (long)(b * HH + h);
        if (which == 0)      qb[(bh * LL + l) * HDD + hd] = val;
        else                 vt[(bh * HDD + hd) * LL + l] = val;
      }
    }
}

// ---------------- fp32 SGEMM: kf = x * Wk^T; padded LDS + single-sync double buffer ----------------
__global__ __launch_bounds__(256) void kgemm_f32(
    const float* __restrict__ X, const float* __restrict__ W,
    float* __restrict__ kf) {
  __shared__ float As[2][16][132];
  __shared__ float Bs[2][16][68];
  int tid = threadIdx.x;
  int n0 = blockIdx.x * 64;
  int m0 = blockIdx.y * 128;
  int am = tid >> 2;
  int ak4 = (tid & 3) * 4;
  int tn = tid & 15, tm = tid >> 4;
  float acc[8][4] = {};
  const float* pA0 = X + (long)(m0 + am) * DD + ak4;
  const float* pA1 = X + (long)(m0 + 64 + am) * DD + ak4;
  const float* pB  = W + (long)(n0 + am) * DD + ak4;
  float4 xa0 = *(const float4*)(pA0);
  float4 xa1 = *(const float4*)(pA1);
  float4 wb0 = *(const float4*)(pB);
#pragma unroll
  for (int j = 0; j < 4; j++) {
    As[0][ak4 + j][am]      = ((const float*)&xa0)[j];
    As[0][ak4 + j][64 + am] = ((const float*)&xa1)[j];
    Bs[0][ak4 + j][am]      = ((const float*)&wb0)[j];
  }
  __syncthreads();
  for (int k0 = 0; k0 < DD; k0 += 16) {
    int cur = (k0 >> 4) & 1;
    bool more = (k0 + 16 < DD);
    if (more) {
      xa0 = *(const float4*)(pA0 + k0 + 16);
      xa1 = *(const float4*)(pA1 + k0 + 16);
      wb0 = *(const float4*)(pB + k0 + 16);
    }
#pragma unroll
    for (int k = 0; k < 16; k++) {
      float4 a0 = *(const float4*)&As[cur][k][tm * 8];
      float4 a1 = *(const float4*)&As[cur][k][tm * 8 + 4];
      float4 bv = *(const float4*)&Bs[cur][k][tn * 4];
#pragma unroll
      for (int i = 0; i < 4; i++)
#pragma unroll
        for (int j = 0; j < 4; j++) {
          acc[i][j]     = fmaf(((const float*)&a0)[i], ((const float*)&bv)[j], acc[i][j]);
          acc[4 + i][j] = fmaf(((const float*)&a1)[i], ((const float*)&bv)[j], acc[4 + i][j]);
        }
    }
    if (more) {
#pragma unroll
      for (int j = 0; j < 4; j++) {
        As[cur ^ 1][ak4 + j][am]      = ((const float*)&xa0)[j];
        As[cur ^ 1][ak4 + j][64 + am] = ((const float*)&xa1)[j];
        Bs[cur ^ 1][ak4 + j][am]      = ((const float*)&wb0)[j];
      }
      __syncthreads();
    }
  }
  int h = n0 >> 6;
#pragma unroll
  for (int i = 0; i < 8; i++) {
    int m = m0 + tm * 8 + i;
    int b = m >> 11, l = m & 2047;
    float4 o;
    ((float*)&o)[0] = acc[i][0]; ((float*)&o)[1] = acc[i][1];
    ((float*)&o)[2] = acc[i][2]; ((float*)&o)[3] = acc[i][3];
    *(float4*)(kf + (((long)(b * HH + h) * LL + l) * HDD) + tn * 4) = o;
  }
}

// ---------------- VQ via split-bf16 MFMA + margin-gated fp32 rescore ----------------
// dot(k,c) ~= k_hi*c_hi + k_hi*c_lo + k_lo*c_hi  (sigma ~6e-5 on d^2);
// top-2 per row; if gap <= 1/64 rescore both exactly in fp32 -> exact fp32 argmin.
__global__ __launch_bounds__(256) void vq_mfma(
    const float* __restrict__ kf, const float* __restrict__ cb,
    const float* __restrict__ c2, const unsigned short* __restrict__ cbb,
    const unsigned short* __restrict__ cbl,
    unsigned short* __restrict__ khat, float* __restrict__ scodes,
    float* __restrict__ lsum) {
  __shared__ int finalIdx[64];
  int tid = threadIdx.x, wave = tid >> 6, lane = tid & 63;
  int quad = lane >> 4, col = lane & 15;
  int rb = blockIdx.x;       // 32 row-tiles of 64
  int bh = blockIdx.y;       // 32
  int h = bh & 15;
  int rbase = rb * 64 + wave * 16;
  // load this lane's slice of kf rows: row rbase+col, dims quad*8..+8 and 32+quad*8..+8
  const float* kp = kf + ((long)bh * LL + rbase + col) * HDD + quad * 8;
  float fv[16];
  {
    float4 t0 = *(const float4*)(kp);
    float4 t1 = *(const float4*)(kp + 4);
    float4 t2 = *(const float4*)(kp + 32);
    float4 t3 = *(const float4*)(kp + 36);
    fv[0]=t0.x; fv[1]=t0.y; fv[2]=t0.z; fv[3]=t0.w;
    fv[4]=t1.x; fv[5]=t1.y; fv[6]=t1.z; fv[7]=t1.w;
    fv[8]=t2.x; fv[9]=t2.y; fv[10]=t2.z; fv[11]=t2.w;
    fv[12]=t3.x; fv[13]=t3.y; fv[14]=t3.z; fv[15]=t3.w;
  }
  float k2 = 0.f;
#pragma unroll
  for (int j = 0; j < 16; j++) k2 = fmaf(fv[j], fv[j], k2);
  k2 += __shfl_xor(k2, 16);
  k2 += __shfl_xor(k2, 32);
  // split k into hi/lo bf16 fragments
  u16x8 kh0u, kh1u, kl0u, kl1u;
#pragma unroll
  for (int j = 0; j < 8; j++) {
    unsigned short hi = f2bf(fv[j]);
    kh0u[j] = hi; kl0u[j] = f2bf(fv[j] - bf2f(hi));
    unsigned short hi2 = f2bf(fv[8 + j]);
    kh1u[j] = hi2; kl1u[j] = f2bf(fv[8 + j] - bf2f(hi2));
  }
  bf16x8 bh0 = __builtin_bit_cast(bf16x8, kh0u);
  bf16x8 bh1 = __builtin_bit_cast(bf16x8, kh1u);
  bf16x8 bl0 = __builtin_bit_cast(bf16x8, kl0u);
  bf16x8 bl1 = __builtin_bit_cast(bf16x8, kl1u);
  const unsigned short* cbbh = cbb + (long)h * NC * HDD;
  const unsigned short* cblh = cbl + (long)h * NC * HDD;
  const float* c2h = c2 + h * NC;
  float b1v = 1e38f, b2v = 1e38f;
  int b1i = 0x7fffffff, b2i = 0x7fffffff;
  for (int ch = 0; ch < 32; ch++) {
    long base = (long)(ch * 16 + col) * HDD + quad * 8;
    bf16x8 ah0 = *(const bf16x8*)(cbbh + base);
    bf16x8 ah1 = *(const bf16x8*)(cbbh + base + 32);
    bf16x8 al0 = *(const bf16x8*)(cblh + base);
    bf16x8 al1 = *(const bf16x8*)(cblh + base + 32);
    f32x4 acc = {};
    acc = __builtin_amdgcn_mfma_f32_16x16x32_bf16(ah0, bh0, acc, 0, 0, 0);
    acc = __builtin_amdgcn_mfma_f32_16x16x32_bf16(ah1, bh1, acc, 0, 0, 0);
    acc = __builtin_amdgcn_mfma_f32_16x16x32_bf16(al0, bh0, acc, 0, 0, 0);
    acc = __builtin_amdgcn_mfma_f32_16x16x32_bf16(al1, bh1, acc, 0, 0, 0);
    acc = __builtin_amdgcn_mfma_f32_16x16x32_bf16(ah0, bl0, acc, 0, 0, 0);
    acc = __builtin_amdgcn_mfma_f32_16x16x32_bf16(ah1, bl1, acc, 0, 0, 0);
    f32x4 c2v = *(const f32x4*)(c2h + ch * 16 + quad * 4);
#pragma unroll
    for (int r = 0; r < 4; r++) {
      float val = c2v[r] - 2.0f * acc[r];
      int idx = ch * 16 + quad * 4 + r;
      if (val < b1v || (val == b1v && idx < b1i)) {
        b2v = b1v; b2i = b1i; b1v = val; b1i = idx;
      } else if (val < b2v || (val == b2v && idx < b2i)) {
        b2v = val; b2i = idx;
      }
    }
  }
  // merge top-2 across quads (lanes same col hold same row)
#pragma unroll
  for (int d = 16; d <= 32; d <<= 1) {
    float o1v = __shfl_xor(b1v, d); int o1i = __shfl_xor(b1i, d);
    float o2v = __shfl_xor(b2v, d); int o2i = __shfl_xor(b2i, d);
    if (o1v < b1v || (o1v == b1v && o1i < b1i)) {
      float nv; int ni;
      if (b1v < o2v || (b1v == o2v && b1i < o2i)) { nv = b1v; ni = b1i; }
      else { nv = o2v; ni = o2i; }
      b1v = o1v; b1i = o1i; b2v = nv; b2i = ni;
    } else {
      if (o1v < b2v || (o1v == b2v && o1i < b2i)) { b2v = o1v; b2i = o1i; }
    }
  }
  const float DMARG = 0.015625f;
  float part = 0.f;
  int widx = b1i;
  if (lane < 16) {
    if (b2v - b1v > DMARG) {
      part = k2 + b1v;
    } else {
      // exact fp32 rescore of both candidates
      const float* krow = kf + ((long)bh * LL + rbase + lane) * HDD;
      const float* c1p = cb + ((long)h * NC + b1i) * HDD;
      const float* c2p = cb + ((long)h * NC + b2i) * HDD;
      float s1 = 0.f, s2 = 0.f;
      for (int j = 0; j < HDD; j++) {
        float kv = krow[j];
        float d1 = kv - c1p[j]; s1 = fmaf(d1, d1, s1);
        float d2 = kv - c2p[j]; s2 = fmaf(d2, d2, s2);
      }
      if (s2 < s1 || (s2 == s1 && b2i < b1i)) { widx = b2i; part = s2; }
      else { widx = b1i; part = s1; }
    }
  }
  // block-wide l_commit partial (inactive lanes contribute 0)
  part += __shfl_xor(part, 1);  part += __shfl_xor(part, 2);
  part += __shfl_xor(part, 4);  part += __shfl_xor(part, 8);
  part += __shfl_xor(part, 16); part += __shfl_xor(part, 32);
  if (lane == 0) atomicAdd(lsum, part);
  if (lane < 16) {
    scodes[(long)bh * LL + rbase + lane] = (float)widx;
    finalIdx[wave * 16 + lane] = widx;
  }
  __syncthreads();
  // cooperative khat gather: thread t -> block-row t>>2, 16-elem segment (t&3)
  {
    int r = tid >> 2, p = (tid & 3) * 16;
    int code = finalIdx[r];
    const unsigned short* src = cbb + ((long)h * NC + code) * HDD + p;
    unsigned short* dst = khat + ((long)bh * LL + rb * 64 + r) * HDD + p;
    *(u16x8*)(dst)     = *(const u16x8*)(src);
    *(u16x8*)(dst + 8) = *(const u16x8*)(src + 8);
  }
}

// ---------------- flash attention: paired q-tiles (i, 31-i), no-max softmax ----------------
__global__ __launch_bounds__(256) void attn_kernel(
    const unsigned short* __restrict__ qb, const unsigned short* __restrict__ khat,
    const unsigned short* __restrict__ vt, unsigned short* __restrict__ attnb) {
  __shared__ __align__(16) unsigned short Pbuf[4][2][16 * 72];
  int tid = threadIdx.x, wave = tid >> 6, lane = tid & 63;
  int quad = lane >> 4, col = lane & 15;
  int pi = blockIdx.x;          // 0..15: pairs q-tile pi with 31-pi
  int bh = blockIdx.y;
  int b = bh >> 4, h = bh & 15;
  int ta = pi, tb = 31 - pi;    // ta < tb always
  int qbA = ta * 64 + wave * 16;
  int qbB = tb * 64 + wave * 16;
  const unsigned short* qrA = qb + ((long)bh * LL + qbA + col) * HDD;
  const unsigned short* qrB = qb + ((long)bh * LL + qbB + col) * HDD;
  bf16x8 aqA0 = *(const bf16x8*)(qrA + quad * 8);
  bf16x8 aqA1 = *(const bf16x8*)(qrA + 32 + quad * 8);
  bf16x8 aqB0 = *(const bf16x8*)(qrB + quad * 8);
  bf16x8 aqB1 = *(const bf16x8*)(qrB + 32 + quad * 8);
  float lA[4] = {0.f, 0.f, 0.f, 0.f}, lB[4] = {0.f, 0.f, 0.f, 0.f};
  f32x4 oA[4] = {}, oB[4] = {};
  unsigned short* PA = Pbuf[wave][0];
  unsigned short* PB = Pbuf[wave][1];
  const unsigned short* kh = khat + (long)bh * LL * HDD;
  const unsigned short* vh = vt + (long)bh * HDD * LL;
  const float SCL = 0.18033688011112042f;  // log2(e) / 8 -> exp2 softmax
  for (int kt = 0; kt <= tb; kt++) {
    int kbase = kt * 64;
    bool actA = (kt <= ta);
    f32x4 zA[4], zB[4];
    for (int nt = 0; nt < 4; nt++) {
      const unsigned short* krow = kh + (long)(kbase + nt * 16 + col) * HDD;
      bf16x8 k0 = *(const bf16x8*)(krow + quad * 8);
      bf16x8 k1 = *(const bf16x8*)(krow + 32 + quad * 8);
      f32x4 z = {};
      z = __builtin_amdgcn_mfma_f32_16x16x32_bf16(aqB0, k0, z, 0, 0, 0);
      z = __builtin_amdgcn_mfma_f32_16x16x32_bf16(aqB1, k1, z, 0, 0, 0);
      zB[nt] = z;
      if (actA) {
        f32x4 y = {};
        y = __builtin_amdgcn_mfma_f32_16x16x32_bf16(aqA0, k0, y, 0, 0, 0);
        y = __builtin_amdgcn_mfma_f32_16x16x32_bf16(aqA1, k1, y, 0, 0, 0);
        zA[nt] = y;
      }
    }
    for (int nt = 0; nt < 4; nt++) {
      int key = kbase + nt * 16 + col;
      for (int r = 0; r < 4; r++) {
        float sc = zB[nt][r] * SCL;
        if (kt == tb && key > qbB + quad * 4 + r) sc = -1e30f;
        float p = exp2f(sc);
        lB[r] += p;
        PB[(quad * 4 + r) * 72 + nt * 16 + col] = f2bf(p);
      }
    }
    if (actA) {
      for (int nt = 0; nt < 4; nt++) {
        int key = kbase + nt * 16 + col;
        for (int r = 0; r < 4; r++) {
          float sc = zA[nt][r] * SCL;
          if (kt == ta && key > qbA + quad * 4 + r) sc = -1e30f;
          float p = exp2f(sc);
          lA[r] += p;
          PA[(quad * 4 + r) * 72 + nt * 16 + col] = f2bf(p);
        }
      }
    }
    bf16x8 apB0 = *(const bf16x8*)(PB + col * 72 + quad * 8);
    bf16x8 apB1 = *(const bf16x8*)(PB + col * 72 + 32 + quad * 8);
    bf16x8 apA0, apA1;
    if (actA) {
      apA0 = *(const bf16x8*)(PA + col * 72 + quad * 8);
      apA1 = *(const bf16x8*)(PA + col * 72 + 32 + quad * 8);
    }
    for (int nt = 0; nt < 4; nt++) {
      const unsigned short* vrow = vh + (long)(nt * 16 + col) * LL + kbase;
      bf16x8 v0 = *(const bf16x8*)(vrow + quad * 8);
      bf16x8 v1 = *(const bf16x8*)(vrow + 32 + quad * 8);
      oB[nt] = __builtin_amdgcn_mfma_f32_16x16x32_bf16(apB0, v0, oB[nt], 0, 0, 0);
      oB[nt] = __builtin_amdgcn_mfma_f32_16x16x32_bf16(apB1, v1, oB[nt], 0, 0, 0);
      if (actA) {
        oA[nt] = __builtin_amdgcn_mfma_f32_16x16x32_bf16(apA0, v0, oA[nt], 0, 0, 0);
        oA[nt] = __builtin_amdgcn_mfma_f32_16x16x32_bf16(apA1, v1, oA[nt], 0, 0, 0);
      }
    }
  }
  float invA[4], invB[4];
  for (int r = 0; r < 4; r++) {
    float t = lA[r];
    t += __shfl_xor(t, 1); t += __shfl_xor(t, 2);
    t += __shfl_xor(t, 4); t += __shfl_xor(t, 8);
    invA[r] = 1.0f / t;
    float u = lB[r];
    u += __shfl_xor(u, 1); u += __shfl_xor(u, 2);
    u += __shfl_xor(u, 4); u += __shfl_xor(u, 8);
    invB[r] = 1.0f / u;
  }
  for (int r = 0; r < 4; r++) {
    int rowA = qbA + quad * 4 + r;
    int rowB = qbB + quad * 4 + r;
    for (int nt = 0; nt < 4; nt++) {
      int hd = nt * 16 + col;
      attnb[((long)b * LL + rowA) * DD + h * HDD + hd] = f2bf(oA[nt][r] * invA[r]);
      attnb[((long)b * LL + rowB) * DD + h * HDD + hd] = f2bf(oB[nt][r] * invB[r]);
    }
  }
}

// ---------------- GEMM2: out = attn * Wo^T (fp32 store) ----------------
__global__ __launch_bounds__(256) void gemm_out(
    const unsigned short* __restrict__ attnb, const unsigned short* __restrict__ wob,
    float* __restrict__ out) {
  __shared__ __align__(16) unsigned short As[128 * 32];
  __shared__ __align__(16) unsigned short Bs[128 * 32];
  int tid = threadIdx.x;
  int wave = tid >> 6, lane = tid & 63;
  int quad = lane >> 4, col = lane & 15;
  int m0 = blockIdx.y * 128;
  int n0 = blockIdx.x * 128;
  f32x4 acc[4][4] = {};
  int row_in = (wave << 4) + (lane >> 2);
  int seg = lane & 3;
  const unsigned short* gA0 = attnb + (long)(m0 + row_in) * DD + seg * 8;
  const unsigned short* gA1 = attnb + (long)(m0 + 64 + row_in) * DD + seg * 8;
  const unsigned short* gB0 = wob + (long)(n0 + row_in) * DD + seg * 8;
  const unsigned short* gB1 = wob + (long)(n0 + 64 + row_in) * DD + seg * 8;
  unsigned short* lA0 = As + wave * 512;
  unsigned short* lA1 = As + 2048 + wave * 512;
  unsigned short* lB0 = Bs + wave * 512;
  unsigned short* lB1 = Bs + 2048 + wave * 512;
  int wm = wave & 1, wn = wave >> 1;
  const unsigned short* pa = As + (wm * 64 + col) * 32 + quad * 8;
  const unsigned short* pb = Bs + (wn * 64 + col) * 32 + quad * 8;
  for (int kk = 0; kk < DD; kk += 32) {
    __syncthreads();
    load_lds16(gA0 + kk, lA0);
    load_lds16(gA1 + kk, lA1);
    load_lds16(gB0 + kk, lB0);
    load_lds16(gB1 + kk, lB1);
    __syncthreads();
    bf16x8 af[4], bfr[4];
    for (int t = 0; t < 4; t++) af[t]  = *(const bf16x8*)(pa + t * 512);
    for (int t = 0; t < 4; t++) bfr[t] = *(const bf16x8*)(pb + t * 512);
    for (int mt = 0; mt < 4; mt++)
      for (int nt = 0; nt < 4; nt++)
        acc[mt][nt] = __builtin_amdgcn_mfma_f32_16x16x32_bf16(af[mt], bfr[nt], acc[mt][nt], 0, 0, 0);
  }
  for (int mt = 0; mt < 4; mt++)
    for (int nt = 0; nt < 4; nt++) {
      int mbase = m0 + wm * 64 + mt * 16 + quad * 4;
      int n = n0 + wn * 64 + nt * 16 + col;
      for (int r = 0; r < 4; r++)
        out[(long)(mbase + r) * DD + n] = acc[mt][nt][r];
    }
}

// ---------------- finalize scalars ----------------
__global__ void finalize(const float* __restrict__ lsum, float* __restrict__ out) {
  if (threadIdx.x == 0) {
    float v = lsum[0] / (float)(BB * HH * LL);
    out[4194304] = v;
    out[4194305] = v;
  }
}

extern "C" void kernel_launch(void* const* d_in, const int* in_sizes, int n_in,
                              void* d_out, int out_size, void* d_ws, size_t ws_size,
                              hipStream_t stream) {
  const float* x  = (const float*)d_in[0];
  const float* wq = (const float*)d_in[1];
  const float* wk = (const float*)d_in[2];
  const float* wv = (const float*)d_in[3];
  const float* wo = (const float*)d_in[4];
  const float* cb = (const float*)d_in[5];
  float* out = (float*)d_out;

  char* ws = (char*)d_ws;
  size_t off = 0;
  auto alloc = [&](size_t bytes) {
    void* p = ws + off;
    off = (off + bytes + 255) & ~(size_t)255;
    return p;
  };
  unsigned short* xb    = (unsigned short*)alloc(4194304 * 2);
  unsigned short* wb    = (unsigned short*)alloc(3145728 * 2);
  unsigned short* wob   = (unsigned short*)alloc(1048576 * 2);
  unsigned short* cbb   = (unsigned short*)alloc(524288 * 2);
  unsigned short* cbl   = (unsigned short*)alloc(524288 * 2);
  unsigned short* qb    = (unsigned short*)alloc(4194304 * 2);
  unsigned short* vt    = (unsigned short*)alloc(4194304 * 2);
  unsigned short* khat  = (unsigned short*)alloc(4194304 * 2);
  unsigned short* attnb = (unsigned short*)alloc(4194304 * 2);
  float* kf   = (float*)alloc(4194304 * 4);
  float* c2   = (float*)alloc(8192 * 4);
  float* lsum = (float*)alloc(256);

  cast_all<<<dim3(4096), dim3(256), 0, stream>>>(x, wq, wk, wv, wo, cb, xb, wb, wob, cbb, cbl, lsum);
  c2_kernel<<<dim3(32), dim3(256), 0, stream>>>(cb, c2);
  gemm_qv<<<dim3(16, 32), dim3(256), 0, stream>>>(xb, wb, qb, vt);
  kgemm_f32<<<dim3(16, 32), dim3(256), 0, stream>>>(x, wk, kf);
  vq_mfma<<<dim3(32, 32), dim3(256), 0, stream>>>(kf, cb, c2, cbb, cbl, khat, out + 4194306, lsum);
  attn_kernel<<<dim3(16, 32), dim3(256), 0, stream>>>(qb, khat, vt, attnb);
  gemm_out<<<dim3(8, 32), dim3(256), 0, stream>>>(attnb, wob, out);
  finalize<<<dim3(1), dim3(64), 0, stream>>>(lsum, out);
}